// Round 12
// baseline (27773.782 us; speedup 1.0000x reference)
//
#include <hip/hip_runtime.h>
#include <hip/hip_bf16.h>
#include <cstdint>
#include <cstddef>

#define D 256
#define NTOK 65536
#define KCODES 4096
#define Q_ELEMS (NTOK * D)   // 16777216
#define DELTA 3.0e-3f
#define CAP 36
#define ESCALE 4096.0f           // 2^12 codebook scale for fp8 packing
#define INV2S (-4.8828125e-4f)   // -2 * 2^-12, exact

typedef float f32x4 __attribute__((ext_vector_type(4)));
typedef unsigned short ushort8 __attribute__((ext_vector_type(8)));
typedef unsigned char uchar8 __attribute__((ext_vector_type(8)));

__device__ __forceinline__ void gload_lds16(const float* g, float* l) {
  __builtin_amdgcn_global_load_lds(
      (const __attribute__((address_space(1))) void*)(g),
      (__attribute__((address_space(3))) void*)(l), 16, 0, 0);
}
__device__ __forceinline__ unsigned short f2bf(float f) {
  __hip_bfloat16 h = __float2bfloat16(f);
  unsigned short u;
  __builtin_memcpy(&u, &h, 2);
  return u;
}
__device__ __forceinline__ float bf2f(unsigned short u) {
  __hip_bfloat16 h;
  __builtin_memcpy(&h, &u, 2);
  return __bfloat162float(h);
}
// software f32 -> OCP e4m3fn with RNE (inputs |x| < 448 guaranteed here)
__device__ __forceinline__ unsigned char f2fp8(float x) {
  unsigned int bits;
  __builtin_memcpy(&bits, &x, 4);
  const unsigned char sign = (bits >> 24) & 0x80;
  const float a = __builtin_fabsf(x);
  if (a < 0.015625f) {  // subnormal: m * 2^-9, m = 0..7 (m=8 -> first normal)
    const int m = (int)__builtin_rintf(a * 512.0f);
    return sign | (unsigned char)m;  // m==8 encodes as 0x08 = 2^-6, correct
  }
  const unsigned int u = bits + 0x7FFFF + ((bits >> 20) & 1);  // RNE to 3 man bits
  const int exp8 = (int)((u >> 23) & 0xff) - 127 + 7;
  const unsigned int man3 = (u >> 20) & 7;
  if (exp8 >= 16) return sign | 0x7e;  // clamp to 448 (unreachable for our data)
  return sign | (unsigned char)((exp8 << 3) | man3);
}

// ---------------- kernel 1a: codebook squared norms (f64 -> f32) ----------
__global__ __launch_bounds__(256) void ee_kernel(const float* __restrict__ cb,
                                                 float* __restrict__ se) {
  const int row = blockIdx.x * 4 + (threadIdx.x >> 6);
  const int lane = threadIdx.x & 63;
  const float4 v = reinterpret_cast<const float4*>(cb + (size_t)row * D)[lane];
  double s = (double)v.x * v.x + (double)v.y * v.y +
             (double)v.z * v.z + (double)v.w * v.w;
#pragma unroll
  for (int o = 32; o > 0; o >>= 1) s += __shfl_down(s, o, 64);
  if (lane == 0) se[row] = (float)s;
}

// ---------------- kernel 1b: token squared norms (f64 -> f32) -------------
__global__ __launch_bounds__(256) void xx_kernel(const float* __restrict__ x,
                                                 float* __restrict__ sx) {
  const int row = blockIdx.x * 4 + (threadIdx.x >> 6);
  const int lane = threadIdx.x & 63;
  const float4 v = reinterpret_cast<const float4*>(x + (size_t)row * D)[lane];
  double s = (double)v.x * v.x + (double)v.y * v.y +
             (double)v.z * v.z + (double)v.w * v.w;
#pragma unroll
  for (int o = 32; o > 0; o >>= 1) s += __shfl_down(s, o, 64);
  if (lane == 0) sx[row] = (float)s;
}

// ---------------- kernel 1c: pack codebook -> fp8 LDS-image tiles ---------
// unit (ct = c>>7, kt): [row = c&127][64 k] bytes; byte idx within unit
// = row*64 + (k ^ ((row&7)<<3))  (XOR swizzle baked in; screen stages the
// unit verbatim via global_load_lds and reads with the same XOR).
// Values scaled by 2^12 so they occupy e4m3's normal range.
__global__ __launch_bounds__(256) void pack_e8_kernel(const float* __restrict__ cb,
                                                      unsigned char* __restrict__ bpack) {
  const int gid = blockIdx.x * 256 + threadIdx.x;  // 16384 = 4096 codes x 4 kt
  const int c = gid >> 2;
  const int kt = gid & 3;
  const int row = c & 127;
  const int swz = (row & 7) << 3;
  unsigned char* dst = bpack + ((size_t)((c >> 7) * 4 + kt)) * 8192 + row * 64;
  const float* src = cb + (size_t)c * D + kt * 64;
#pragma unroll
  for (int j = 0; j < 8; ++j) {
    uchar8 o;
#pragma unroll
    for (int e = 0; e < 8; ++e) o[e] = f2fp8(src[j * 8 + e] * ESCALE);
    *reinterpret_cast<uchar8*>(dst + ((j * 8) ^ swz)) = o;
  }
}

// ---------------- kernel 2: fp8 MFMA screening ----------------------------
// Structure = r9/r11's proven screen3 (ring-3, 2-deep prefetch, plain
// __syncthreads, 2 blocks/CU) with B in fp8: unit 16KB -> 8KB halves the
// dominant LDS-read term (82 -> 41 us/CU) and the staging DMA. A = fp8(x)
// in VGPRs (long = 8 bytes); mfma_f32_16x16x32_fp8_fp8 (same shape/acc
// layout as the verified bf16 path; within-lane k-permutations cancel
// between A and B packs). score = fmaf(-2^-11, acc, se) — exact unscale.
// Error budget: sigma_score ~= 2.3e-4 (both operands e4m3, RMS rel 0.036)
// -> DELTA = 3e-3 gives 8.6-sigma capture incl. ref f32-rounding window.
// CAP 36 absorbs the wider candidate window; overflow -> exact full scan.
__global__ __launch_bounds__(256, 2) void screen8_kernel(
    const float* __restrict__ x, const unsigned char* __restrict__ bpack,
    const float* __restrict__ se, unsigned int* __restrict__ ccnt_g,
    unsigned int* __restrict__ cand_g, float* __restrict__ rm_g) {
  __shared__ __attribute__((aligned(16))) unsigned char bbuf[3][8192];   // 24KB
  __shared__ __attribute__((aligned(16))) unsigned short se_lds[KCODES]; // 8KB
  __shared__ unsigned int cand[128][CAP];                                // 18KB
  __shared__ unsigned int ccnt[128];                                     // 0.5KB

  const int tid = threadIdx.x;
  const int lane = tid & 63;
  const int w = tid >> 6;    // 0..3
  const int l15 = lane & 15;
  const int kg = lane >> 4;  // 0..3
  const int swz8 = (l15 & 7) << 3;
  const int tok0 = blockIdx.x * 128;

  if (tid < 128) ccnt[tid] = 0;
  {  // se -> bf16 LDS: each thread converts 16 values
    const float4* s4 = reinterpret_cast<const float4*>(se) + tid * 4;
    const float4 a = s4[0], b = s4[1], c = s4[2], d = s4[3];
    ushort8 o0, o1;
    o0[0] = f2bf(a.x); o0[1] = f2bf(a.y); o0[2] = f2bf(a.z); o0[3] = f2bf(a.w);
    o0[4] = f2bf(b.x); o0[5] = f2bf(b.y); o0[6] = f2bf(b.z); o0[7] = f2bf(b.w);
    o1[0] = f2bf(c.x); o1[1] = f2bf(c.y); o1[2] = f2bf(c.z); o1[3] = f2bf(c.w);
    o1[4] = f2bf(d.x); o1[5] = f2bf(d.y); o1[6] = f2bf(d.z); o1[7] = f2bf(d.w);
    *reinterpret_cast<ushort8*>(&se_lds[tid * 16]) = o0;
    *reinterpret_cast<ushort8*>(&se_lds[tid * 16 + 8]) = o1;
  }

  // A fragments (fp8): 2 row-groups x 8 ksteps, 8 bytes each, static indices
  long ah[2][8];
#pragma unroll
  for (int gi = 0; gi < 2; ++gi) {
    const int t = tok0 + w * 32 + gi * 16 + l15;
    const float* xp = x + (size_t)t * D;
#pragma unroll
    for (int ks = 0; ks < 8; ++ks) {
      const float4 v0 = *reinterpret_cast<const float4*>(xp + ks * 32 + kg * 8);
      const float4 v1 = *reinterpret_cast<const float4*>(xp + ks * 32 + kg * 8 + 4);
      const float xv[8] = {v0.x, v0.y, v0.z, v0.w, v1.x, v1.y, v1.z, v1.w};
      unsigned long long pv = 0;
#pragma unroll
      for (int e = 0; e < 8; ++e)
        pv |= (unsigned long long)f2fp8(xv[e]) << (8 * e);
      ah[gi][ks] = (long)pv;
    }
  }

  // stage one 8KB unit: 4 waves x 2 chunks x (64 lanes x 16B)
  auto STAGE = [&](int u) {
    const char* s = (const char*)bpack + (size_t)u * 8192 + w * 2048 + lane * 16;
    char* d = (char*)&bbuf[u % 3][0] + w * 2048;
    gload_lds16((const float*)s, (float*)d);
    gload_lds16((const float*)(s + 1024), (float*)(d + 1024));
  };

  float rm[2][4];
#pragma unroll
  for (int fr = 0; fr < 2; ++fr)
#pragma unroll
    for (int q = 0; q < 4; ++q) rm[fr][q] = 3.4e38f;

  f32x4 acc[2][8];

  STAGE(0);
  STAGE(1);
  __syncthreads();  // units 0,1 resident; se/ccnt ready

  for (int ct4 = 0; ct4 < 32; ++ct4) {
#pragma unroll
    for (int kt = 0; kt < 4; ++kt) {  // kt compile-time: ah[] stays in VGPRs
      const int u = ct4 * 4 + kt;
      if (u + 2 < 128) STAGE(u + 2);
      if (kt == 0) {
#pragma unroll
        for (int fr = 0; fr < 2; ++fr)
#pragma unroll
          for (int fc = 0; fc < 8; ++fc) acc[fr][fc] = (f32x4){0.f, 0.f, 0.f, 0.f};
      }
      const unsigned char* bb = &bbuf[u % 3][0];
#pragma unroll
      for (int kh = 0; kh < 2; ++kh) {
        const int ks = kt * 2 + kh;  // compile-time
        const unsigned char* bkh = bb + l15 * 64 + ((kh * 32 + kg * 8) ^ swz8);
        long bfrag[8];
#pragma unroll
        for (int fc = 0; fc < 8; ++fc)
          bfrag[fc] = *reinterpret_cast<const long*>(bkh + fc * 1024);
#pragma unroll
        for (int fr = 0; fr < 2; ++fr)
#pragma unroll
          for (int fc = 0; fc < 8; ++fc)
            acc[fr][fc] = __builtin_amdgcn_mfma_f32_16x16x32_fp8_fp8(
                ah[fr][ks], bfrag[fc], acc[fr][fc], 0, 0, 0);
      }
      if (kt == 3) {  // code-tile ct4 finished: mins + candidate inserts
        float sef[8];
#pragma unroll
        for (int fc = 0; fc < 8; ++fc)
          sef[fc] = bf2f(se_lds[ct4 * 128 + fc * 16 + l15]);
#pragma unroll
        for (int fr = 0; fr < 2; ++fr)
#pragma unroll
          for (int q = 0; q < 4; ++q) {
            float m = fmaf(INV2S, acc[fr][0][q], sef[0]);
#pragma unroll
            for (int fc = 1; fc < 8; ++fc)
              m = fminf(m, fmaf(INV2S, acc[fr][fc][q], sef[fc]));
            m = fminf(m, __shfl_xor(m, 1, 64));
            m = fminf(m, __shfl_xor(m, 2, 64));
            m = fminf(m, __shfl_xor(m, 4, 64));
            m = fminf(m, __shfl_xor(m, 8, 64));
            rm[fr][q] = fminf(rm[fr][q], m);
            const float thr = rm[fr][q] + DELTA;
            const int tl = w * 32 + fr * 16 + kg * 4 + q;
#pragma unroll
            for (int fc = 0; fc < 8; ++fc) {
              const float s = fmaf(INV2S, acc[fr][fc][q], sef[fc]);
              if (s <= thr) {
                const unsigned p = atomicAdd(&ccnt[tl], 1u);
                if (p < CAP)
                  cand[tl][p] = ((unsigned)f2bf(s) << 16) |
                                (unsigned)(ct4 * 128 + fc * 16 + l15);
              }
            }
          }
      }
      __syncthreads();  // next unit resident; ring slot (u%3) free for reuse
    }
  }

  if (tid < 128) ccnt_g[tok0 + tid] = ccnt[tid];
  if (l15 == 0) {
#pragma unroll
    for (int fr = 0; fr < 2; ++fr)
#pragma unroll
      for (int q = 0; q < 4; ++q)
        rm_g[tok0 + w * 32 + fr * 16 + kg * 4 + q] = rm[fr][q];
  }
  for (int j = tid; j < 128 * CAP; j += 256)
    cand_g[(size_t)tok0 * CAP + j] = cand[j / CAP][j % CAP];
}

// ---------------- kernel 3: exact-chain rescore (filtered) ----------------
// One thread per token. Filter candidates by unpacked bf16 score <= rm+DELTA,
// then replicate reference f32 semantics bit-for-bit on the survivors:
// sequential fmaf chain d=0..255, dist = fl(fl(sx+se)-2*dot), lex-min.
__global__ __launch_bounds__(256) void rescore_kernel(
    const float* __restrict__ x, const float* __restrict__ cb,
    const float* __restrict__ se, const float* __restrict__ sx,
    const unsigned int* __restrict__ ccnt_g, const unsigned int* __restrict__ cand_g,
    const float* __restrict__ rm_g, int* __restrict__ idx_i,
    float* __restrict__ idxf_out, unsigned int* __restrict__ ovf_count,
    int* __restrict__ ovf_list) {
  const int t = blockIdx.x * 256 + threadIdx.x;
  const unsigned n = ccnt_g[t];
  if (n > CAP) {  // list overflowed: defer to full-scan fallback
    const unsigned p = atomicAdd(ovf_count, 1u);
    ovf_list[p] = t;
    return;
  }
  const float thr = rm_g[t] + DELTA;
  const float sxv = sx[t];
  const float4* xp = reinterpret_cast<const float4*>(x + (size_t)t * D);
  float bq = 3.4e38f;
  int bc = 0x7fffffff;
  for (unsigned k = 0; k < n; ++k) {
    const unsigned pk = cand_g[(size_t)t * CAP + k];
    if (bf2f((unsigned short)(pk >> 16)) > thr) continue;
    const int c = (int)(pk & 0xFFFFu);
    const float4* cp = reinterpret_cast<const float4*>(cb + (size_t)c * D);
    float acc = 0.0f;
#pragma unroll 8
    for (int d4 = 0; d4 < 64; ++d4) {
      const float4 xv = xp[d4];
      const float4 ev = cp[d4];
      acc = fmaf(xv.x, ev.x, acc);
      acc = fmaf(xv.y, ev.y, acc);
      acc = fmaf(xv.z, ev.z, acc);
      acc = fmaf(xv.w, ev.w, acc);
    }
    const float r = sxv + se[c];
    const float q = r - 2.0f * acc;
    if (q < bq || (q == bq && c < bc)) { bq = q; bc = c; }
  }
  idx_i[t] = bc;
  idxf_out[t] = (float)bc;
}

// ---------------- kernel 3b: full-scan fallback for overflowed tokens -----
__global__ __launch_bounds__(256) void ovf_kernel(
    const float* __restrict__ x, const float* __restrict__ cb,
    const float* __restrict__ se, const float* __restrict__ sx,
    const unsigned int* __restrict__ ovf_count, const int* __restrict__ ovf_list,
    int* __restrict__ idx_i, float* __restrict__ idxf_out) {
  __shared__ float bvv[256];
  __shared__ int bii[256];
  const int tid = threadIdx.x;
  const unsigned cnt = *ovf_count;
  for (unsigned i = blockIdx.x; i < cnt; i += gridDim.x) {
    const int t = ovf_list[i];
    const float sxv = sx[t];
    const float4* xp = reinterpret_cast<const float4*>(x + (size_t)t * D);
    float bq = 3.4e38f;
    int bc = 0x7fffffff;
    for (int c = tid; c < KCODES; c += 256) {
      const float4* cp = reinterpret_cast<const float4*>(cb + (size_t)c * D);
      float acc = 0.0f;
#pragma unroll 8
      for (int d4 = 0; d4 < 64; ++d4) {
        const float4 xv = xp[d4];
        const float4 ev = cp[d4];
        acc = fmaf(xv.x, ev.x, acc);
        acc = fmaf(xv.y, ev.y, acc);
        acc = fmaf(xv.z, ev.z, acc);
        acc = fmaf(xv.w, ev.w, acc);
      }
      const float r = sxv + se[c];
      const float q = r - 2.0f * acc;
      if (q < bq || (q == bq && c < bc)) { bq = q; bc = c; }
    }
    bvv[tid] = bq;
    bii[tid] = bc;
    __syncthreads();
    for (int o = 128; o > 0; o >>= 1) {
      if (tid < o) {
        const float v2 = bvv[tid + o];
        const int c2 = bii[tid + o];
        if (v2 < bvv[tid] || (v2 == bvv[tid] && c2 < bii[tid])) {
          bvv[tid] = v2;
          bii[tid] = c2;
        }
      }
      __syncthreads();
    }
    if (tid == 0) {
      idx_i[t] = bii[0];
      idxf_out[t] = (float)bii[0];
    }
    __syncthreads();
  }
}

// ---------------- fallback argmin (tiny-ws path; round-4 kernel) ----------
__global__ __launch_bounds__(256) void argmin_fb_kernel(const float* __restrict__ x,
                                                        const float* __restrict__ cb,
                                                        const float* __restrict__ se,
                                                        const float* __restrict__ sx,
                                                        int* __restrict__ idx_out,
                                                        float* __restrict__ idxf_out) {
  __shared__ __attribute__((aligned(16))) float xs[64 * 128];
  __shared__ __attribute__((aligned(16))) float es[64 * 128];
  const int tid = threadIdx.x;
  const int lane = tid & 63;
  const int w = tid >> 6;
  const int wt = w & 1;
  const int wc = w >> 1;
  const int tgl = lane & 7;
  const int cgl = lane >> 3;
  const int t0 = wt * 64 + tgl * 8;
  const int c0 = wc * 64 + cgl * 8;
  const int tok0 = blockIdx.x * 128;
  float sxf[8];
#pragma unroll
  for (int i = 0; i < 8; ++i) sxf[i] = sx[tok0 + t0 + i];
  float bv[8];
  int bi[8];
#pragma unroll
  for (int i = 0; i < 8; ++i) { bv[i] = 3.4e38f; bi[i] = 0; }
  for (int ct = 0; ct < KCODES / 128; ++ct) {
    float acc[8][8] = {};
    for (int kt = 0; kt < 4; ++kt) {
      __syncthreads();
      {
        const float* xsrc = x + (size_t)tok0 * D + kt * 64;
        const float* esrc = cb + (size_t)(ct * 128) * D + kt * 64;
#pragma unroll
        for (int p = 0; p < 8; ++p) {
          const int idx = p * 256 + tid;
          const int t = idx >> 4;
          const int c = idx & 15;
          const int colp = (t + 8 * (c >> 1)) & 127;
          const float4 xv = *reinterpret_cast<const float4*>(xsrc + (size_t)t * D + c * 4);
          float* xd = &xs[(c * 4) * 128 + colp];
          xd[0] = xv.x; xd[128] = xv.y; xd[256] = xv.z; xd[384] = xv.w;
          const float4 ev = *reinterpret_cast<const float4*>(esrc + (size_t)t * D + c * 4);
          float* ed = &es[(c * 4) * 128 + colp];
          ed[0] = ev.x; ed[128] = ev.y; ed[256] = ev.z; ed[384] = ev.w;
        }
      }
      __syncthreads();
      for (int kp = 0; kp < 8; ++kp) {
        const float* xb = &xs[(kp * 8) * 128 + ((t0 + 8 * kp) & 127)];
        const float* eb = &es[(kp * 8) * 128 + ((c0 + 8 * kp) & 127)];
#pragma unroll
        for (int k2 = 0; k2 < 8; ++k2) {
          const float4 xv0 = *reinterpret_cast<const float4*>(xb + k2 * 128);
          const float4 xv1 = *reinterpret_cast<const float4*>(xb + k2 * 128 + 4);
          const float4 ev0 = *reinterpret_cast<const float4*>(eb + k2 * 128);
          const float4 ev1 = *reinterpret_cast<const float4*>(eb + k2 * 128 + 4);
          const float xa[8] = {xv0.x, xv0.y, xv0.z, xv0.w, xv1.x, xv1.y, xv1.z, xv1.w};
          const float ea[8] = {ev0.x, ev0.y, ev0.z, ev0.w, ev1.x, ev1.y, ev1.z, ev1.w};
#pragma unroll
          for (int i = 0; i < 8; ++i)
#pragma unroll
            for (int j = 0; j < 8; ++j) acc[i][j] = fmaf(xa[i], ea[j], acc[i][j]);
        }
      }
    }
#pragma unroll
    for (int j = 0; j < 8; ++j) {
      const int cidx = ct * 128 + c0 + j;
      const float sef = se[cidx];
#pragma unroll
      for (int i = 0; i < 8; ++i) {
        const float r = sxf[i] + sef;
        const float s = r - 2.0f * acc[i][j];
        if (s < bv[i]) { bv[i] = s; bi[i] = cidx; }
      }
    }
  }
  __syncthreads();
  float* red_val = xs;
  int* red_idx = reinterpret_cast<int*>(xs + 128 * 17);
  const int g = wc * 8 + cgl;
#pragma unroll
  for (int i = 0; i < 8; ++i) {
    red_val[(t0 + i) * 17 + g] = bv[i];
    red_idx[(t0 + i) * 17 + g] = bi[i];
  }
  __syncthreads();
  if (tid < 128) {
    float v = red_val[tid * 17 + 0];
    int ix = red_idx[tid * 17 + 0];
#pragma unroll
    for (int gg = 1; gg < 16; ++gg) {
      const float vv = red_val[tid * 17 + gg];
      const int ii = red_idx[tid * 17 + gg];
      if (vv < v || (vv == v && ii < ix)) { v = vv; ix = ii; }
    }
    idx_out[tok0 + tid] = ix;
    idxf_out[tok0 + tid] = (float)ix;
  }
}

// ---------------- kernel 4: gather, q_st, loss partials, histogram --------
__global__ __launch_bounds__(256) void finalize_kernel(const float* __restrict__ x,
                                                       const float* __restrict__ cb,
                                                       const int* __restrict__ idx,
                                                       float* __restrict__ q_out,
                                                       unsigned int* __restrict__ counts,
                                                       double* __restrict__ partials) {
  __shared__ double tok_s[16];
  const int tid = threadIdx.x;
  const int lt = tid >> 4;
  const int ld = tid & 15;
  const int t = blockIdx.x * 16 + lt;
  const int id = idx[t];
  const float* xp = x + (size_t)t * D + ld * 16;
  const float* ep = cb + (size_t)id * D + ld * 16;
  float* qp = q_out + (size_t)t * D + ld * 16;
  float s = 0.0f;
#pragma unroll
  for (int c = 0; c < 4; ++c) {
    const float4 xv = reinterpret_cast<const float4*>(xp)[c];
    const float4 ev = reinterpret_cast<const float4*>(ep)[c];
    const float d0 = ev.x - xv.x, d1 = ev.y - xv.y;
    const float d2 = ev.z - xv.z, d3 = ev.w - xv.w;
    s = fmaf(d0, d0, s);
    s = fmaf(d1, d1, s);
    s = fmaf(d2, d2, s);
    s = fmaf(d3, d3, s);
    float4 qv;  // q_st = x + (q - x), as the reference computes it
    qv.x = xv.x + d0;
    qv.y = xv.y + d1;
    qv.z = xv.z + d2;
    qv.w = xv.w + d3;
    reinterpret_cast<float4*>(qp)[c] = qv;
  }
#pragma unroll
  for (int o = 8; o > 0; o >>= 1) s += __shfl_down(s, o, 16);
  if (ld == 0) {
    atomicAdd(&counts[id], 1u);
    tok_s[lt] = (double)s;
  }
  __syncthreads();
  if (tid == 0) {
    double bs = 0.0;
    for (int i = 0; i < 16; ++i) bs += tok_s[i];
    partials[blockIdx.x] = bs;
  }
}

// ---------------- kernel 5: scalar reductions ----------------
__global__ __launch_bounds__(256) void final_kernel(const unsigned int* __restrict__ counts,
                                                    const double* __restrict__ partials,
                                                    float* __restrict__ loss_out,
                                                    float* __restrict__ perp_out) {
  __shared__ double sh[256];
  const int tid = threadIdx.x;
  double ls = 0.0;
  for (int i = tid; i < NTOK / 16; i += 256) ls += partials[i];
  sh[tid] = ls;
  __syncthreads();
#pragma unroll
  for (int o = 128; o > 0; o >>= 1) {
    if (tid < o) sh[tid] += sh[tid + o];
    __syncthreads();
  }
  if (tid == 0) *loss_out = (float)(sh[0] * (1.25 / (256.0 * 65536.0)));
  __syncthreads();
  double hs = 0.0;
  for (int i = tid; i < KCODES; i += 256) {
    const float p = (float)counts[i] / 65536.0f;
    hs += (double)(p * logf(p + 1e-10f));
  }
  sh[tid] = hs;
  __syncthreads();
#pragma unroll
  for (int o = 128; o > 0; o >>= 1) {
    if (tid < o) sh[tid] += sh[tid + o];
    __syncthreads();
  }
  if (tid == 0) *perp_out = expf((float)(-sh[0]));
}

extern "C" void kernel_launch(void* const* d_in, const int* in_sizes, int n_in,
                              void* d_out, int out_size, void* d_ws, size_t ws_size,
                              hipStream_t stream) {
  (void)in_sizes; (void)n_in; (void)out_size;
  const float* x = (const float*)d_in[0];
  const float* cb = (const float*)d_in[1];

  float* out = (float*)d_out;
  float* q_out = out;                                  // [0, 16777216)
  float* loss_out = out + (size_t)Q_ELEMS;             // [16777216]
  float* perp_out = out + (size_t)Q_ELEMS + 1;         // [16777217]
  float* idxf_out = out + (size_t)Q_ELEMS + 2;         // [16777218, +65536)

  // ws layout (bytes):
  //   se f32[4096]           @0
  //   counts u32[4096]       @16K
  //   partials f64[4096]     @32K
  //   idx i32[65536]         @128K
  //   sx f32[65536]          @384K
  //   ovf_count u32          @640K
  //   ovf_list i32[65536]    @644K
  //   ccnt_g u32[65536]      @1M
  //   rm_g f32[65536]        @1.5M
  //   cand_g u32[65536*36]   @2M   (9.44MB)
  //   bpack fp8[4096*256]    @12M  (1MB)
  char* ws = (char*)d_ws;
  float* se = (float*)(ws + 0);
  unsigned int* counts = (unsigned int*)(ws + (16 << 10));
  double* partials = (double*)(ws + (32 << 10));
  int* idx_i = (int*)(ws + (128 << 10));
  float* sx = (float*)(ws + (384 << 10));
  unsigned int* ovf_count = (unsigned int*)(ws + (640 << 10));
  int* ovf_list = (int*)(ws + (644 << 10));
  unsigned int* ccnt_g = (unsigned int*)(ws + (1 << 20));
  float* rm_g = (float*)(ws + (3 << 19));
  unsigned int* cand_g = (unsigned int*)(ws + (2 << 20));
  unsigned char* bpack = (unsigned char*)(ws + (12 << 20));

  hipMemsetAsync(counts, 0, KCODES * sizeof(unsigned int), stream);
  hipMemsetAsync(ovf_count, 0, sizeof(unsigned int), stream);
  ee_kernel<<<KCODES / 4, 256, 0, stream>>>(cb, se);
  xx_kernel<<<NTOK / 4, 256, 0, stream>>>(x, sx);

  if (ws_size >= (size_t)20 * 1024 * 1024) {
    pack_e8_kernel<<<64, 256, 0, stream>>>(cb, bpack);
    screen8_kernel<<<NTOK / 128, 256, 0, stream>>>(x, bpack, se, ccnt_g, cand_g,
                                                   rm_g);
    rescore_kernel<<<NTOK / 256, 256, 0, stream>>>(x, cb, se, sx, ccnt_g, cand_g,
                                                   rm_g, idx_i, idxf_out,
                                                   ovf_count, ovf_list);
    ovf_kernel<<<64, 256, 0, stream>>>(x, cb, se, sx, ovf_count, ovf_list,
                                       idx_i, idxf_out);
  } else {
    argmin_fb_kernel<<<NTOK / 128, 256, 0, stream>>>(x, cb, se, sx, idx_i, idxf_out);
  }
  finalize_kernel<<<NTOK / 16, 256, 0, stream>>>(x, cb, idx_i, q_out, counts, partials);
  final_kernel<<<1, 256, 0, stream>>>(counts, partials, loss_out, perp_out);
}

// Round 13
// 444.434 us; speedup vs baseline: 62.4924x; 62.4924x over previous
//
#include <hip/hip_runtime.h>
#include <hip/hip_bf16.h>
#include <cstdint>
#include <cstddef>

#define D 256
#define NTOK 65536
#define KCODES 4096
#define Q_ELEMS (NTOK * D)   // 16777216
#define DELTA 3.0e-4f
#define CAP 24

typedef short bf16x8 __attribute__((ext_vector_type(8)));
typedef float f32x4 __attribute__((ext_vector_type(4)));
typedef unsigned short ushort8 __attribute__((ext_vector_type(8)));

__device__ __forceinline__ unsigned short f2bf(float f) {
  __hip_bfloat16 h = __float2bfloat16(f);
  unsigned short u;
  __builtin_memcpy(&u, &h, 2);
  return u;
}
__device__ __forceinline__ float bf2f(unsigned short u) {
  __hip_bfloat16 h;
  __builtin_memcpy(&h, &u, 2);
  return __bfloat162float(h);
}

// ---------------- kernel 1a: codebook squared norms (f64 -> f32) ----------
__global__ __launch_bounds__(256) void ee_kernel(const float* __restrict__ cb,
                                                 float* __restrict__ se) {
  const int row = blockIdx.x * 4 + (threadIdx.x >> 6);
  const int lane = threadIdx.x & 63;
  const float4 v = reinterpret_cast<const float4*>(cb + (size_t)row * D)[lane];
  double s = (double)v.x * v.x + (double)v.y * v.y +
             (double)v.z * v.z + (double)v.w * v.w;
#pragma unroll
  for (int o = 32; o > 0; o >>= 1) s += __shfl_down(s, o, 64);
  if (lane == 0) se[row] = (float)s;
}

// ---------------- kernel 1b: token squared norms (fallback path only) -----
__global__ __launch_bounds__(256) void xx_kernel(const float* __restrict__ x,
                                                 float* __restrict__ sx) {
  const int row = blockIdx.x * 4 + (threadIdx.x >> 6);
  const int lane = threadIdx.x & 63;
  const float4 v = reinterpret_cast<const float4*>(x + (size_t)row * D)[lane];
  double s = (double)v.x * v.x + (double)v.y * v.y +
             (double)v.z * v.z + (double)v.w * v.w;
#pragma unroll
  for (int o = 32; o > 0; o >>= 1) s += __shfl_down(s, o, 64);
  if (lane == 0) sx[row] = (float)s;
}

// ---------------- kernel 1c: pack codebook -> fragment-linear bf16 --------
// kh-block g = (ct*4+kt)*2+kh holds 8 fragments (fc=0..7), each 1KB laid
// [lane][8 bf16] with lane = kg*16+l15: one global_load_dwordx4 per lane
// fetches a whole fragment, fully coalesced. Code c -> (ct=c>>7, fc=(c&127)>>4,
// l15=c&15); k -> (kt=k>>6, kh, kg, e).
__global__ __launch_bounds__(256) void pack_e_kernel(const float* __restrict__ cb,
                                                     unsigned short* __restrict__ bpack) {
  const int gid = blockIdx.x * 256 + threadIdx.x;  // 16384 = 4096 codes x 4 kt
  const int c = gid >> 2;
  const int kt = gid & 3;
  const int row = c & 127;
  const int fc = row >> 4;
  const int l15 = row & 15;
  const int unit = (c >> 7) * 4 + kt;
  const float* src = cb + (size_t)c * D + kt * 64;
#pragma unroll
  for (int kh = 0; kh < 2; ++kh)
#pragma unroll
    for (int kg = 0; kg < 4; ++kg) {
      ushort8 o;
#pragma unroll
      for (int e = 0; e < 8; ++e) o[e] = f2bf(src[kh * 32 + kg * 8 + e]);
      *reinterpret_cast<ushort8*>(
          bpack + (size_t)unit * 8192 + (kh * 8 + fc) * 512 +
          (kg * 16 + l15) * 8) = o;
    }
}

// ---------------- kernel 2: barrier-free MFMA screening -------------------
// 256 thr / 4 waves / 128 tokens per block; 512 blocks. NO LDS staging, NO
// main-loop barriers: B fragments are read directly from the 2MB
// fragment-linear pack (L2-resident; all waves read the same sequence ->
// heavy L1 reuse). One kh-block (8 frags) prefetched ahead in registers
// (b0/b1 alternate, all indices compile-time). Math identical to the
// r11-verified bf16 screen: d~ = se - 2*bf16(x).e_hi via mfma 16x16x32;
// candidates (bf16(score)<<16)|idx inserted when s <= running_min + DELTA.
// Capture bound: winner <= rm_final + 1.74e-4 + 6e-5 < DELTA = 3e-4.
__global__ __launch_bounds__(256, 2) void screeng_kernel(
    const float* __restrict__ x, const unsigned short* __restrict__ bpack,
    const float* __restrict__ se, unsigned int* __restrict__ ccnt_g,
    unsigned int* __restrict__ cand_g, float* __restrict__ rm_g) {
  __shared__ __attribute__((aligned(16))) unsigned short se_lds[KCODES]; // 8KB
  __shared__ unsigned int cand[128][CAP];                                // 12KB
  __shared__ unsigned int ccnt[128];                                     // 0.5KB

  const int tid = threadIdx.x;
  const int lane = tid & 63;
  const int w = tid >> 6;    // 0..3
  const int l15 = lane & 15;
  const int kg = lane >> 4;  // 0..3
  const int tok0 = blockIdx.x * 128;

  if (tid < 128) ccnt[tid] = 0;
  {  // se -> bf16 LDS: each thread converts 16 values
    const float4* s4 = reinterpret_cast<const float4*>(se) + tid * 4;
    const float4 a = s4[0], b = s4[1], c = s4[2], d = s4[3];
    ushort8 o0, o1;
    o0[0] = f2bf(a.x); o0[1] = f2bf(a.y); o0[2] = f2bf(a.z); o0[3] = f2bf(a.w);
    o0[4] = f2bf(b.x); o0[5] = f2bf(b.y); o0[6] = f2bf(b.z); o0[7] = f2bf(b.w);
    o1[0] = f2bf(c.x); o1[1] = f2bf(c.y); o1[2] = f2bf(c.z); o1[3] = f2bf(c.w);
    o1[4] = f2bf(d.x); o1[5] = f2bf(d.y); o1[6] = f2bf(d.z); o1[7] = f2bf(d.w);
    *reinterpret_cast<ushort8*>(&se_lds[tid * 16]) = o0;
    *reinterpret_cast<ushort8*>(&se_lds[tid * 16 + 8]) = o1;
  }
  __syncthreads();  // ccnt/se ready before any wave inserts (no more barriers)

  // A fragments (hi-only bf16): 2 row-groups x 8 ksteps, static indices
  bf16x8 ah[2][8];
#pragma unroll
  for (int gi = 0; gi < 2; ++gi) {
    const int t = tok0 + w * 32 + gi * 16 + l15;
    const float* xp = x + (size_t)t * D;
#pragma unroll
    for (int ks = 0; ks < 8; ++ks) {
      const float4 v0 = *reinterpret_cast<const float4*>(xp + ks * 32 + kg * 8);
      const float4 v1 = *reinterpret_cast<const float4*>(xp + ks * 32 + kg * 8 + 4);
      const float xv[8] = {v0.x, v0.y, v0.z, v0.w, v1.x, v1.y, v1.z, v1.w};
      bf16x8 h;
#pragma unroll
      for (int e = 0; e < 8; ++e) h[e] = (short)f2bf(xv[e]);
      ah[gi][ks] = h;
    }
  }

  // load one kh-block (8 fragments x 1KB) into registers
  auto LOADKH = [&](bf16x8 (&dst)[8], int g) {
    const unsigned short* ub = bpack + (size_t)g * 4096 + lane * 8;
#pragma unroll
    for (int fc = 0; fc < 8; ++fc)
      dst[fc] = *reinterpret_cast<const bf16x8*>(ub + fc * 512);
  };

  float rm[2][4];
#pragma unroll
  for (int fr = 0; fr < 2; ++fr)
#pragma unroll
    for (int q = 0; q < 4; ++q) rm[fr][q] = 3.4e38f;

  f32x4 acc[2][8];
  bf16x8 b0[8], b1[8];
  LOADKH(b0, 0);

  for (int ct4 = 0; ct4 < 32; ++ct4) {
#pragma unroll
    for (int fr = 0; fr < 2; ++fr)
#pragma unroll
      for (int fc = 0; fc < 8; ++fc) acc[fr][fc] = (f32x4){0.f, 0.f, 0.f, 0.f};
#pragma unroll
    for (int p = 0; p < 8; ++p) {  // p = kt*2+kh, static; A kstep = p
      const int gn = ct4 * 8 + p + 1;
      if ((p & 1) == 0) {
        if (gn < 256) LOADKH(b1, gn);
#pragma unroll
        for (int fr = 0; fr < 2; ++fr)
#pragma unroll
          for (int fc = 0; fc < 8; ++fc)
            acc[fr][fc] = __builtin_amdgcn_mfma_f32_16x16x32_bf16(
                ah[fr][p], b0[fc], acc[fr][fc], 0, 0, 0);
      } else {
        if (gn < 256) LOADKH(b0, gn);
#pragma unroll
        for (int fr = 0; fr < 2; ++fr)
#pragma unroll
          for (int fc = 0; fc < 8; ++fc)
            acc[fr][fc] = __builtin_amdgcn_mfma_f32_16x16x32_bf16(
                ah[fr][p], b1[fc], acc[fr][fc], 0, 0, 0);
      }
    }
    // code-tile finished: mins + candidate inserts (scores computed once)
    {
      float sef[8];
#pragma unroll
      for (int fc = 0; fc < 8; ++fc)
        sef[fc] = bf2f(se_lds[ct4 * 128 + fc * 16 + l15]);
#pragma unroll
      for (int fr = 0; fr < 2; ++fr)
#pragma unroll
        for (int q = 0; q < 4; ++q) {
          float s8[8];
#pragma unroll
          for (int fc = 0; fc < 8; ++fc)
            s8[fc] = fmaf(-2.0f, acc[fr][fc][q], sef[fc]);
          float m = s8[0];
#pragma unroll
          for (int fc = 1; fc < 8; ++fc) m = fminf(m, s8[fc]);
          m = fminf(m, __shfl_xor(m, 1, 64));
          m = fminf(m, __shfl_xor(m, 2, 64));
          m = fminf(m, __shfl_xor(m, 4, 64));
          m = fminf(m, __shfl_xor(m, 8, 64));
          rm[fr][q] = fminf(rm[fr][q], m);
          const float thr = rm[fr][q] + DELTA;
          const int tl = w * 32 + fr * 16 + kg * 4 + q;
#pragma unroll
          for (int fc = 0; fc < 8; ++fc) {
            if (s8[fc] <= thr) {
              const unsigned p2 = atomicAdd(&ccnt[tl], 1u);
              if (p2 < CAP)
                cand[tl][p2] = ((unsigned)f2bf(s8[fc]) << 16) |
                               (unsigned)(ct4 * 128 + fc * 16 + l15);
            }
          }
        }
    }
  }

  __syncthreads();
  if (tid < 128) ccnt_g[tok0 + tid] = ccnt[tid];
  if (l15 == 0) {
#pragma unroll
    for (int fr = 0; fr < 2; ++fr)
#pragma unroll
      for (int q = 0; q < 4; ++q)
        rm_g[tok0 + w * 32 + fr * 16 + kg * 4 + q] = rm[fr][q];
  }
  for (int j = tid; j < 128 * CAP; j += 256)
    cand_g[(size_t)tok0 * CAP + j] = cand[j / CAP][j % CAP];
}

// ---------------- kernel 3: exact-chain rescore (sx inline, filtered) -----
// One thread per token. sx computed inline in f64 (bit-safe: se < half-ulp
// of sx always, so fl(sx+se)=sx and the argmin is sx-invariant; empirically
// verified in r9's passing run). Filter candidates by unpacked bf16 score
// <= rm+DELTA, then replicate reference f32 semantics bit-for-bit:
// sequential fmaf chain d=0..255, dist = fl(fl(sx+se)-2*dot), lex-min.
__global__ __launch_bounds__(256) void rescore_kernel(
    const float* __restrict__ x, const float* __restrict__ cb,
    const float* __restrict__ se, const unsigned int* __restrict__ ccnt_g,
    const unsigned int* __restrict__ cand_g, const float* __restrict__ rm_g,
    int* __restrict__ idx_i, float* __restrict__ idxf_out,
    unsigned int* __restrict__ ovf_count, int* __restrict__ ovf_list) {
  const int t = blockIdx.x * 256 + threadIdx.x;
  const unsigned n = ccnt_g[t];
  if (n > CAP) {  // list overflowed: defer to full-scan fallback
    const unsigned p = atomicAdd(ovf_count, 1u);
    ovf_list[p] = t;
    return;
  }
  const float4* xp = reinterpret_cast<const float4*>(x + (size_t)t * D);
  double sxd = 0.0;
  for (int d4 = 0; d4 < 64; ++d4) {
    const float4 v = xp[d4];
    sxd += (double)v.x * v.x + (double)v.y * v.y +
           (double)v.z * v.z + (double)v.w * v.w;
  }
  const float sxv = (float)sxd;
  const float thr = rm_g[t] + DELTA;
  float bq = 3.4e38f;
  int bc = 0x7fffffff;
  for (unsigned k = 0; k < n; ++k) {
    const unsigned pk = cand_g[(size_t)t * CAP + k];
    if (bf2f((unsigned short)(pk >> 16)) > thr) continue;
    const int c = (int)(pk & 0xFFFFu);
    const float4* cp = reinterpret_cast<const float4*>(cb + (size_t)c * D);
    float acc = 0.0f;
#pragma unroll 8
    for (int d4 = 0; d4 < 64; ++d4) {
      const float4 xv = xp[d4];
      const float4 ev = cp[d4];
      acc = fmaf(xv.x, ev.x, acc);
      acc = fmaf(xv.y, ev.y, acc);
      acc = fmaf(xv.z, ev.z, acc);
      acc = fmaf(xv.w, ev.w, acc);
    }
    const float r = sxv + se[c];
    const float q = r - 2.0f * acc;
    if (q < bq || (q == bq && c < bc)) { bq = q; bc = c; }
  }
  idx_i[t] = bc;
  idxf_out[t] = (float)bc;
}

// ---------------- kernel 3b: full-scan fallback for overflowed tokens -----
__global__ __launch_bounds__(256) void ovf_kernel(
    const float* __restrict__ x, const float* __restrict__ cb,
    const float* __restrict__ se, const unsigned int* __restrict__ ovf_count,
    const int* __restrict__ ovf_list, int* __restrict__ idx_i,
    float* __restrict__ idxf_out) {
  __shared__ float bvv[256];
  __shared__ int bii[256];
  __shared__ double shd[256];
  const int tid = threadIdx.x;
  const unsigned cnt = *ovf_count;
  for (unsigned i = blockIdx.x; i < cnt; i += gridDim.x) {
    const int t = ovf_list[i];
    const float xv1 = x[(size_t)t * D + tid];
    shd[tid] = (double)xv1 * xv1;
    __syncthreads();
    for (int o = 128; o > 0; o >>= 1) {
      if (tid < o) shd[tid] += shd[tid + o];
      __syncthreads();
    }
    const float sxv = (float)shd[0];
    __syncthreads();
    const float4* xp = reinterpret_cast<const float4*>(x + (size_t)t * D);
    float bq = 3.4e38f;
    int bc = 0x7fffffff;
    for (int c = tid; c < KCODES; c += 256) {
      const float4* cp = reinterpret_cast<const float4*>(cb + (size_t)c * D);
      float acc = 0.0f;
#pragma unroll 8
      for (int d4 = 0; d4 < 64; ++d4) {
        const float4 xv = xp[d4];
        const float4 ev = cp[d4];
        acc = fmaf(xv.x, ev.x, acc);
        acc = fmaf(xv.y, ev.y, acc);
        acc = fmaf(xv.z, ev.z, acc);
        acc = fmaf(xv.w, ev.w, acc);
      }
      const float r = sxv + se[c];
      const float q = r - 2.0f * acc;
      if (q < bq || (q == bq && c < bc)) { bq = q; bc = c; }
    }
    bvv[tid] = bq;
    bii[tid] = bc;
    __syncthreads();
    for (int o = 128; o > 0; o >>= 1) {
      if (tid < o) {
        const float v2 = bvv[tid + o];
        const int c2 = bii[tid + o];
        if (v2 < bvv[tid] || (v2 == bvv[tid] && c2 < bii[tid])) {
          bvv[tid] = v2;
          bii[tid] = c2;
        }
      }
      __syncthreads();
    }
    if (tid == 0) {
      idx_i[t] = bii[0];
      idxf_out[t] = (float)bii[0];
    }
    __syncthreads();
  }
}

// ---------------- fallback argmin (tiny-ws path; round-4 kernel) ----------
__global__ __launch_bounds__(256) void argmin_fb_kernel(const float* __restrict__ x,
                                                        const float* __restrict__ cb,
                                                        const float* __restrict__ se,
                                                        const float* __restrict__ sx,
                                                        int* __restrict__ idx_out,
                                                        float* __restrict__ idxf_out) {
  __shared__ __attribute__((aligned(16))) float xs[64 * 128];
  __shared__ __attribute__((aligned(16))) float es[64 * 128];
  const int tid = threadIdx.x;
  const int lane = tid & 63;
  const int w = tid >> 6;
  const int wt = w & 1;
  const int wc = w >> 1;
  const int tgl = lane & 7;
  const int cgl = lane >> 3;
  const int t0 = wt * 64 + tgl * 8;
  const int c0 = wc * 64 + cgl * 8;
  const int tok0 = blockIdx.x * 128;
  float sxf[8];
#pragma unroll
  for (int i = 0; i < 8; ++i) sxf[i] = sx[tok0 + t0 + i];
  float bv[8];
  int bi[8];
#pragma unroll
  for (int i = 0; i < 8; ++i) { bv[i] = 3.4e38f; bi[i] = 0; }
  for (int ct = 0; ct < KCODES / 128; ++ct) {
    float acc[8][8] = {};
    for (int kt = 0; kt < 4; ++kt) {
      __syncthreads();
      {
        const float* xsrc = x + (size_t)tok0 * D + kt * 64;
        const float* esrc = cb + (size_t)(ct * 128) * D + kt * 64;
#pragma unroll
        for (int p = 0; p < 8; ++p) {
          const int idx = p * 256 + tid;
          const int t = idx >> 4;
          const int c = idx & 15;
          const int colp = (t + 8 * (c >> 1)) & 127;
          const float4 xv = *reinterpret_cast<const float4*>(xsrc + (size_t)t * D + c * 4);
          float* xd = &xs[(c * 4) * 128 + colp];
          xd[0] = xv.x; xd[128] = xv.y; xd[256] = xv.z; xd[384] = xv.w;
          const float4 ev = *reinterpret_cast<const float4*>(esrc + (size_t)t * D + c * 4);
          float* ed = &es[(c * 4) * 128 + colp];
          ed[0] = ev.x; ed[128] = ev.y; ed[256] = ev.z; ed[384] = ev.w;
        }
      }
      __syncthreads();
      for (int kp = 0; kp < 8; ++kp) {
        const float* xb = &xs[(kp * 8) * 128 + ((t0 + 8 * kp) & 127)];
        const float* eb = &es[(kp * 8) * 128 + ((c0 + 8 * kp) & 127)];
#pragma unroll
        for (int k2 = 0; k2 < 8; ++k2) {
          const float4 xv0 = *reinterpret_cast<const float4*>(xb + k2 * 128);
          const float4 xv1 = *reinterpret_cast<const float4*>(xb + k2 * 128 + 4);
          const float4 ev0 = *reinterpret_cast<const float4*>(eb + k2 * 128);
          const float4 ev1 = *reinterpret_cast<const float4*>(eb + k2 * 128 + 4);
          const float xa[8] = {xv0.x, xv0.y, xv0.z, xv0.w, xv1.x, xv1.y, xv1.z, xv1.w};
          const float ea[8] = {ev0.x, ev0.y, ev0.z, ev0.w, ev1.x, ev1.y, ev1.z, ev1.w};
#pragma unroll
          for (int i = 0; i < 8; ++i)
#pragma unroll
            for (int j = 0; j < 8; ++j) acc[i][j] = fmaf(xa[i], ea[j], acc[i][j]);
        }
      }
    }
#pragma unroll
    for (int j = 0; j < 8; ++j) {
      const int cidx = ct * 128 + c0 + j;
      const float sef = se[cidx];
#pragma unroll
      for (int i = 0; i < 8; ++i) {
        const float r = sxf[i] + sef;
        const float s = r - 2.0f * acc[i][j];
        if (s < bv[i]) { bv[i] = s; bi[i] = cidx; }
      }
    }
  }
  __syncthreads();
  float* red_val = xs;
  int* red_idx = reinterpret_cast<int*>(xs + 128 * 17);
  const int g = wc * 8 + cgl;
#pragma unroll
  for (int i = 0; i < 8; ++i) {
    red_val[(t0 + i) * 17 + g] = bv[i];
    red_idx[(t0 + i) * 17 + g] = bi[i];
  }
  __syncthreads();
  if (tid < 128) {
    float v = red_val[tid * 17 + 0];
    int ix = red_idx[tid * 17 + 0];
#pragma unroll
    for (int gg = 1; gg < 16; ++gg) {
      const float vv = red_val[tid * 17 + gg];
      const int ii = red_idx[tid * 17 + gg];
      if (vv < v || (vv == v && ii < ix)) { v = vv; ix = ii; }
    }
    idx_out[tok0 + tid] = ix;
    idxf_out[tok0 + tid] = (float)ix;
  }
}

// ---------------- kernel 4: gather, q_st, loss partials, histogram --------
__global__ __launch_bounds__(256) void finalize_kernel(const float* __restrict__ x,
                                                       const float* __restrict__ cb,
                                                       const int* __restrict__ idx,
                                                       float* __restrict__ q_out,
                                                       unsigned int* __restrict__ counts,
                                                       double* __restrict__ partials) {
  __shared__ double tok_s[16];
  const int tid = threadIdx.x;
  const int lt = tid >> 4;
  const int ld = tid & 15;
  const int t = blockIdx.x * 16 + lt;
  const int id = idx[t];
  const float* xp = x + (size_t)t * D + ld * 16;
  const float* ep = cb + (size_t)id * D + ld * 16;
  float* qp = q_out + (size_t)t * D + ld * 16;
  float s = 0.0f;
#pragma unroll
  for (int c = 0; c < 4; ++c) {
    const float4 xv = reinterpret_cast<const float4*>(xp)[c];
    const float4 ev = reinterpret_cast<const float4*>(ep)[c];
    const float d0 = ev.x - xv.x, d1 = ev.y - xv.y;
    const float d2 = ev.z - xv.z, d3 = ev.w - xv.w;
    s = fmaf(d0, d0, s);
    s = fmaf(d1, d1, s);
    s = fmaf(d2, d2, s);
    s = fmaf(d3, d3, s);
    float4 qv;  // q_st = x + (q - x), as the reference computes it
    qv.x = xv.x + d0;
    qv.y = xv.y + d1;
    qv.z = xv.z + d2;
    qv.w = xv.w + d3;
    reinterpret_cast<float4*>(qp)[c] = qv;
  }
#pragma unroll
  for (int o = 8; o > 0; o >>= 1) s += __shfl_down(s, o, 16);
  if (ld == 0) {
    atomicAdd(&counts[id], 1u);
    tok_s[lt] = (double)s;
  }
  __syncthreads();
  if (tid == 0) {
    double bs = 0.0;
    for (int i = 0; i < 16; ++i) bs += tok_s[i];
    partials[blockIdx.x] = bs;
  }
}

// ---------------- kernel 5: scalar reductions ----------------
__global__ __launch_bounds__(256) void final_kernel(const unsigned int* __restrict__ counts,
                                                    const double* __restrict__ partials,
                                                    float* __restrict__ loss_out,
                                                    float* __restrict__ perp_out) {
  __shared__ double sh[256];
  const int tid = threadIdx.x;
  double ls = 0.0;
  for (int i = tid; i < NTOK / 16; i += 256) ls += partials[i];
  sh[tid] = ls;
  __syncthreads();
#pragma unroll
  for (int o = 128; o > 0; o >>= 1) {
    if (tid < o) sh[tid] += sh[tid + o];
    __syncthreads();
  }
  if (tid == 0) *loss_out = (float)(sh[0] * (1.25 / (256.0 * 65536.0)));
  __syncthreads();
  double hs = 0.0;
  for (int i = tid; i < KCODES; i += 256) {
    const float p = (float)counts[i] / 65536.0f;
    hs += (double)(p * logf(p + 1e-10f));
  }
  sh[tid] = hs;
  __syncthreads();
#pragma unroll
  for (int o = 128; o > 0; o >>= 1) {
    if (tid < o) sh[tid] += sh[tid + o];
    __syncthreads();
  }
  if (tid == 0) *perp_out = expf((float)(-sh[0]));
}

extern "C" void kernel_launch(void* const* d_in, const int* in_sizes, int n_in,
                              void* d_out, int out_size, void* d_ws, size_t ws_size,
                              hipStream_t stream) {
  (void)in_sizes; (void)n_in; (void)out_size;
  const float* x = (const float*)d_in[0];
  const float* cb = (const float*)d_in[1];

  float* out = (float*)d_out;
  float* q_out = out;                                  // [0, 16777216)
  float* loss_out = out + (size_t)Q_ELEMS;             // [16777216]
  float* perp_out = out + (size_t)Q_ELEMS + 1;         // [16777217]
  float* idxf_out = out + (size_t)Q_ELEMS + 2;         // [16777218, +65536)

  // ws layout (bytes):
  //   se f32[4096]           @0
  //   counts u32[4096]       @16K
  //   partials f64[4096]     @32K
  //   idx i32[65536]         @128K
  //   sx f32[65536]          @384K  (fallback only)
  //   ovf_count u32          @640K
  //   ovf_list i32[65536]    @644K
  //   ccnt_g u32[65536]      @1M
  //   rm_g f32[65536]        @1.5M
  //   cand_g u32[65536*24]   @2M   (6MB)
  //   bpack bf16[4096*256]   @12M  (2MB)
  char* ws = (char*)d_ws;
  float* se = (float*)(ws + 0);
  unsigned int* counts = (unsigned int*)(ws + (16 << 10));
  double* partials = (double*)(ws + (32 << 10));
  int* idx_i = (int*)(ws + (128 << 10));
  float* sx = (float*)(ws + (384 << 10));
  unsigned int* ovf_count = (unsigned int*)(ws + (640 << 10));
  int* ovf_list = (int*)(ws + (644 << 10));
  unsigned int* ccnt_g = (unsigned int*)(ws + (1 << 20));
  float* rm_g = (float*)(ws + (3 << 19));
  unsigned int* cand_g = (unsigned int*)(ws + (2 << 20));
  unsigned short* bpack = (unsigned short*)(ws + (12 << 20));

  hipMemsetAsync(counts, 0, KCODES * sizeof(unsigned int), stream);
  hipMemsetAsync(ovf_count, 0, sizeof(unsigned int), stream);
  ee_kernel<<<KCODES / 4, 256, 0, stream>>>(cb, se);

  if (ws_size >= (size_t)20 * 1024 * 1024) {
    pack_e_kernel<<<64, 256, 0, stream>>>(cb, bpack);
    screeng_kernel<<<NTOK / 128, 256, 0, stream>>>(x, bpack, se, ccnt_g, cand_g,
                                                   rm_g);
    rescore_kernel<<<NTOK / 256, 256, 0, stream>>>(x, cb, se, ccnt_g, cand_g,
                                                   rm_g, idx_i, idxf_out,
                                                   ovf_count, ovf_list);
    ovf_kernel<<<64, 256, 0, stream>>>(x, cb, se, ovf_count, ovf_list,
                                       idx_i, idxf_out);
  } else {
    xx_kernel<<<NTOK / 4, 256, 0, stream>>>(x, sx);
    argmin_fb_kernel<<<NTOK / 128, 256, 0, stream>>>(x, cb, se, sx, idx_i, idxf_out);
  }
  finalize_kernel<<<NTOK / 16, 256, 0, stream>>>(x, cb, idx_i, q_out, counts, partials);
  final_kernel<<<1, 256, 0, stream>>>(counts, partials, loss_out, perp_out);
}

// Round 14
// 358.122 us; speedup vs baseline: 77.5539x; 1.2410x over previous
//
#include <hip/hip_runtime.h>
#include <hip/hip_bf16.h>
#include <cstdint>
#include <cstddef>

#define D 256
#define NTOK 65536
#define KCODES 4096
#define Q_ELEMS (NTOK * D)   // 16777216
#define DELTA 3.0e-4f
#define CAP 24

typedef short bf16x8 __attribute__((ext_vector_type(8)));
typedef float f32x4 __attribute__((ext_vector_type(4)));
typedef unsigned short ushort8 __attribute__((ext_vector_type(8)));

__device__ __forceinline__ void gload_lds16(const float* g, float* l) {
  __builtin_amdgcn_global_load_lds(
      (const __attribute__((address_space(1))) void*)(g),
      (__attribute__((address_space(3))) void*)(l), 16, 0, 0);
}
__device__ __forceinline__ unsigned short f2bf(float f) {
  __hip_bfloat16 h = __float2bfloat16(f);
  unsigned short u;
  __builtin_memcpy(&u, &h, 2);
  return u;
}
__device__ __forceinline__ float bf2f(unsigned short u) {
  __hip_bfloat16 h;
  __builtin_memcpy(&h, &u, 2);
  return __bfloat162float(h);
}

// ---------------- kernel 1a: codebook squared norms (f64 -> f32) ----------
__global__ __launch_bounds__(256) void ee_kernel(const float* __restrict__ cb,
                                                 float* __restrict__ se) {
  const int row = blockIdx.x * 4 + (threadIdx.x >> 6);
  const int lane = threadIdx.x & 63;
  const float4 v = reinterpret_cast<const float4*>(cb + (size_t)row * D)[lane];
  double s = (double)v.x * v.x + (double)v.y * v.y +
             (double)v.z * v.z + (double)v.w * v.w;
#pragma unroll
  for (int o = 32; o > 0; o >>= 1) s += __shfl_down(s, o, 64);
  if (lane == 0) se[row] = (float)s;
}

// ---------------- kernel 1b: token squared norms (fallback path only) -----
__global__ __launch_bounds__(256) void xx_kernel(const float* __restrict__ x,
                                                 float* __restrict__ sx) {
  const int row = blockIdx.x * 4 + (threadIdx.x >> 6);
  const int lane = threadIdx.x & 63;
  const float4 v = reinterpret_cast<const float4*>(x + (size_t)row * D)[lane];
  double s = (double)v.x * v.x + (double)v.y * v.y +
             (double)v.z * v.z + (double)v.w * v.w;
#pragma unroll
  for (int o = 32; o > 0; o >>= 1) s += __shfl_down(s, o, 64);
  if (lane == 0) sx[row] = (float)s;
}

// ---------------- kernel 1c: pack codebook e_hi -> LDS-image bf16 tiles ---
__global__ __launch_bounds__(256) void pack_e_kernel(const float* __restrict__ cb,
                                                     unsigned short* __restrict__ bpack) {
  const int gid = blockIdx.x * 256 + threadIdx.x;  // 16384 = 4096 codes x 4 kt
  const int c = gid >> 2;
  const int kt = gid & 3;
  const int row = c & 127;
  const int swz = (row & 7) << 3;
  unsigned short* dst = bpack + ((size_t)((c >> 7) * 4 + kt)) * 8192 + row * 64;
  const float* src = cb + (size_t)c * D + kt * 64;
#pragma unroll
  for (int j = 0; j < 8; ++j) {
    ushort8 o;
#pragma unroll
    for (int e = 0; e < 8; ++e) o[e] = f2bf(src[j * 8 + e]);
    *reinterpret_cast<ushort8*>(dst + ((j * 8) ^ swz)) = o;
  }
}

// ---------------- kernel 2: MFMA screening (r11 + counted vmcnt) ----------
// 256 thr / 4 waves / 128 tokens per block; 512 blocks. Ring-3 bbuf (48KB),
// 2-deep prefetch, LDS 68.5KB -> 2 blocks/CU (r11's proven config) with T4
// counted-vmcnt barriers: s_waitcnt vmcnt(4) + raw s_barrier keeps this
// iteration's 4 stage loads (unit u+2) in flight across the barrier while
// guaranteeing unit u+1 landed (r8-verified counting). Prologue drains
// vmcnt(0) so the count covers only stage loads. Math identical to
// r11-passing: d~ = se - 2*bf16(x).e_hi via mfma 16x16x32; candidates
// (bf16(score)<<16)|idx inserted when s <= running_min + DELTA.
// Capture bound: winner <= rm_final + 1.74e-4 + 6e-5 < DELTA = 3e-4.
__global__ __launch_bounds__(256, 2) void screen5_kernel(
    const float* __restrict__ x, const unsigned short* __restrict__ bpack,
    const float* __restrict__ se, unsigned int* __restrict__ ccnt_g,
    unsigned int* __restrict__ cand_g, float* __restrict__ rm_g) {
  __shared__ __attribute__((aligned(16))) unsigned short bbuf[3][8192];  // 48KB
  __shared__ __attribute__((aligned(16))) unsigned short se_lds[KCODES]; // 8KB
  __shared__ unsigned int cand[128][CAP];                                // 12KB
  __shared__ unsigned int ccnt[128];                                     // 0.5KB

  const int tid = threadIdx.x;
  const int lane = tid & 63;
  const int w = tid >> 6;    // 0..3
  const int l15 = lane & 15;
  const int kg = lane >> 4;  // 0..3
  const int tok0 = blockIdx.x * 128;

  if (tid < 128) ccnt[tid] = 0;
  {  // se -> bf16 LDS: each thread converts 16 values
    const float4* s4 = reinterpret_cast<const float4*>(se) + tid * 4;
    const float4 a = s4[0], b = s4[1], c = s4[2], d = s4[3];
    ushort8 o0, o1;
    o0[0] = f2bf(a.x); o0[1] = f2bf(a.y); o0[2] = f2bf(a.z); o0[3] = f2bf(a.w);
    o0[4] = f2bf(b.x); o0[5] = f2bf(b.y); o0[6] = f2bf(b.z); o0[7] = f2bf(b.w);
    o1[0] = f2bf(c.x); o1[1] = f2bf(c.y); o1[2] = f2bf(c.z); o1[3] = f2bf(c.w);
    o1[4] = f2bf(d.x); o1[5] = f2bf(d.y); o1[6] = f2bf(d.z); o1[7] = f2bf(d.w);
    *reinterpret_cast<ushort8*>(&se_lds[tid * 16]) = o0;
    *reinterpret_cast<ushort8*>(&se_lds[tid * 16 + 8]) = o1;
  }

  // A fragments (hi-only bf16): 2 row-groups x 8 ksteps, static indices
  bf16x8 ah[2][8];
#pragma unroll
  for (int gi = 0; gi < 2; ++gi) {
    const int t = tok0 + w * 32 + gi * 16 + l15;
    const float* xp = x + (size_t)t * D;
#pragma unroll
    for (int ks = 0; ks < 8; ++ks) {
      const float4 v0 = *reinterpret_cast<const float4*>(xp + ks * 32 + kg * 8);
      const float4 v1 = *reinterpret_cast<const float4*>(xp + ks * 32 + kg * 8 + 4);
      const float xv[8] = {v0.x, v0.y, v0.z, v0.w, v1.x, v1.y, v1.z, v1.w};
      bf16x8 h;
#pragma unroll
      for (int e = 0; e < 8; ++e) h[e] = (short)f2bf(xv[e]);
      ah[gi][ks] = h;
    }
  }

  // stage one 16KB unit: 4 waves x 4 chunks x (64 lanes x 16B)
  auto STAGE = [&](int u) {
    const char* s = (const char*)bpack + (size_t)u * 16384 + w * 4096 + lane * 16;
    char* d = (char*)&bbuf[u % 3][0] + w * 4096;
    gload_lds16((const float*)s, (float*)d);
    gload_lds16((const float*)(s + 1024), (float*)(d + 1024));
    gload_lds16((const float*)(s + 2048), (float*)(d + 2048));
    gload_lds16((const float*)(s + 3072), (float*)(d + 3072));
  };

  float rm[2][4];
#pragma unroll
  for (int fr = 0; fr < 2; ++fr)
#pragma unroll
    for (int q = 0; q < 4; ++q) rm[fr][q] = 3.4e38f;

  f32x4 acc[2][8];

  // drain A/se loads so vmcnt below counts ONLY stage loads (r8 pattern)
  __builtin_amdgcn_sched_barrier(0);
  asm volatile("s_waitcnt vmcnt(0)" ::: "memory");
  STAGE(0);
  STAGE(1);
  asm volatile("s_waitcnt vmcnt(4) lgkmcnt(0)" ::: "memory");
  __builtin_amdgcn_s_barrier();
  __builtin_amdgcn_sched_barrier(0);

  for (int ct4 = 0; ct4 < 32; ++ct4) {
#pragma unroll
    for (int kt = 0; kt < 4; ++kt) {  // kt compile-time: ah[] stays in VGPRs
      const int u = ct4 * 4 + kt;
      if (u + 2 < 128) STAGE(u + 2);
      if (kt == 0) {
#pragma unroll
        for (int fr = 0; fr < 2; ++fr)
#pragma unroll
          for (int fc = 0; fc < 8; ++fc) acc[fr][fc] = (f32x4){0.f, 0.f, 0.f, 0.f};
      }
      const unsigned short* bb = &bbuf[u % 3][0];
#pragma unroll
      for (int kh = 0; kh < 2; ++kh) {
        const int ks = kt * 2 + kh;  // compile-time
        bf16x8 bfrag[8];
#pragma unroll
        for (int fc = 0; fc < 8; ++fc) {
          const int row = fc * 16 + l15;
          const int off = row * 64 + ((kh * 32 + kg * 8) ^ ((row & 7) << 3));
          bfrag[fc] = *reinterpret_cast<const bf16x8*>(bb + off);
        }
#pragma unroll
        for (int fr = 0; fr < 2; ++fr)
#pragma unroll
          for (int fc = 0; fc < 8; ++fc)
            acc[fr][fc] = __builtin_amdgcn_mfma_f32_16x16x32_bf16(
                ah[fr][ks], bfrag[fc], acc[fr][fc], 0, 0, 0);
      }
      if (kt == 3) {  // code-tile ct4 finished: mins + candidate inserts
        float sef[8];
#pragma unroll
        for (int fc = 0; fc < 8; ++fc)
          sef[fc] = bf2f(se_lds[ct4 * 128 + fc * 16 + l15]);
#pragma unroll
        for (int fr = 0; fr < 2; ++fr)
#pragma unroll
          for (int q = 0; q < 4; ++q) {
            float m = fmaf(-2.0f, acc[fr][0][q], sef[0]);
#pragma unroll
            for (int fc = 1; fc < 8; ++fc)
              m = fminf(m, fmaf(-2.0f, acc[fr][fc][q], sef[fc]));
            m = fminf(m, __shfl_xor(m, 1, 64));
            m = fminf(m, __shfl_xor(m, 2, 64));
            m = fminf(m, __shfl_xor(m, 4, 64));
            m = fminf(m, __shfl_xor(m, 8, 64));
            rm[fr][q] = fminf(rm[fr][q], m);
            const float thr = rm[fr][q] + DELTA;
            const int tl = w * 32 + fr * 16 + kg * 4 + q;
#pragma unroll
            for (int fc = 0; fc < 8; ++fc) {
              const float s = fmaf(-2.0f, acc[fr][fc][q], sef[fc]);
              if (s <= thr) {
                const unsigned p = atomicAdd(&ccnt[tl], 1u);
                if (p < CAP)
                  cand[tl][p] = ((unsigned)f2bf(s) << 16) |
                                (unsigned)(ct4 * 128 + fc * 16 + l15);
              }
            }
          }
      }
      // counted-vmcnt barrier: this iteration's stage (u+2) stays in
      // flight; unit u+1 guaranteed landed. u==126: last stage (127) was
      // issued at u==125, must be resident for u==127 -> vmcnt(0).
      if (u != 127) {
        if (u != 126) asm volatile("s_waitcnt vmcnt(4)" ::: "memory");
        else          asm volatile("s_waitcnt vmcnt(0)" ::: "memory");
        __builtin_amdgcn_s_barrier();
        __builtin_amdgcn_sched_barrier(0);
      }
    }
  }

  __syncthreads();  // full drain (DS atomics) before writeback
  if (tid < 128) ccnt_g[tok0 + tid] = ccnt[tid];
  if (l15 == 0) {
#pragma unroll
    for (int fr = 0; fr < 2; ++fr)
#pragma unroll
      for (int q = 0; q < 4; ++q)
        rm_g[tok0 + w * 32 + fr * 16 + kg * 4 + q] = rm[fr][q];
  }
  for (int j = tid; j < 128 * CAP; j += 256)
    cand_g[(size_t)tok0 * CAP + j] = cand[j / CAP][j % CAP];
}

// ---------------- kernel 3: exact-chain rescore (sx inline, filtered) -----
// One thread per token. sx computed inline in f64 (bit-safe: se < half-ulp
// of sx always, so fl(sx+se)=sx and the argmin is sx-invariant; empirically
// verified in r9/r13 passing runs). Filter candidates by unpacked bf16
// score <= rm+DELTA, then replicate reference f32 semantics bit-for-bit:
// sequential fmaf chain d=0..255, dist = fl(fl(sx+se)-2*dot), lex-min.
__global__ __launch_bounds__(256) void rescore_kernel(
    const float* __restrict__ x, const float* __restrict__ cb,
    const float* __restrict__ se, const unsigned int* __restrict__ ccnt_g,
    const unsigned int* __restrict__ cand_g, const float* __restrict__ rm_g,
    int* __restrict__ idx_i, float* __restrict__ idxf_out,
    unsigned int* __restrict__ ovf_count, int* __restrict__ ovf_list) {
  const int t = blockIdx.x * 256 + threadIdx.x;
  const unsigned n = ccnt_g[t];
  if (n > CAP) {  // list overflowed: defer to full-scan fallback
    const unsigned p = atomicAdd(ovf_count, 1u);
    ovf_list[p] = t;
    return;
  }
  const float4* xp = reinterpret_cast<const float4*>(x + (size_t)t * D);
  double sxd = 0.0;
  for (int d4 = 0; d4 < 64; ++d4) {
    const float4 v = xp[d4];
    sxd += (double)v.x * v.x + (double)v.y * v.y +
           (double)v.z * v.z + (double)v.w * v.w;
  }
  const float sxv = (float)sxd;
  const float thr = rm_g[t] + DELTA;
  float bq = 3.4e38f;
  int bc = 0x7fffffff;
  for (unsigned k = 0; k < n; ++k) {
    const unsigned pk = cand_g[(size_t)t * CAP + k];
    if (bf2f((unsigned short)(pk >> 16)) > thr) continue;
    const int c = (int)(pk & 0xFFFFu);
    const float4* cp = reinterpret_cast<const float4*>(cb + (size_t)c * D);
    float acc = 0.0f;
#pragma unroll 8
    for (int d4 = 0; d4 < 64; ++d4) {
      const float4 xv = xp[d4];
      const float4 ev = cp[d4];
      acc = fmaf(xv.x, ev.x, acc);
      acc = fmaf(xv.y, ev.y, acc);
      acc = fmaf(xv.z, ev.z, acc);
      acc = fmaf(xv.w, ev.w, acc);
    }
    const float r = sxv + se[c];
    const float q = r - 2.0f * acc;
    if (q < bq || (q == bq && c < bc)) { bq = q; bc = c; }
  }
  idx_i[t] = bc;
  idxf_out[t] = (float)bc;
}

// ---------------- kernel 3b: full-scan fallback for overflowed tokens -----
__global__ __launch_bounds__(256) void ovf_kernel(
    const float* __restrict__ x, const float* __restrict__ cb,
    const float* __restrict__ se, const unsigned int* __restrict__ ovf_count,
    const int* __restrict__ ovf_list, int* __restrict__ idx_i,
    float* __restrict__ idxf_out) {
  __shared__ float bvv[256];
  __shared__ int bii[256];
  __shared__ double shd[256];
  const int tid = threadIdx.x;
  const unsigned cnt = *ovf_count;
  for (unsigned i = blockIdx.x; i < cnt; i += gridDim.x) {
    const int t = ovf_list[i];
    const float xv1 = x[(size_t)t * D + tid];
    shd[tid] = (double)xv1 * xv1;
    __syncthreads();
    for (int o = 128; o > 0; o >>= 1) {
      if (tid < o) shd[tid] += shd[tid + o];
      __syncthreads();
    }
    const float sxv = (float)shd[0];
    __syncthreads();
    const float4* xp = reinterpret_cast<const float4*>(x + (size_t)t * D);
    float bq = 3.4e38f;
    int bc = 0x7fffffff;
    for (int c = tid; c < KCODES; c += 256) {
      const float4* cp = reinterpret_cast<const float4*>(cb + (size_t)c * D);
      float acc = 0.0f;
#pragma unroll 8
      for (int d4 = 0; d4 < 64; ++d4) {
        const float4 xv = xp[d4];
        const float4 ev = cp[d4];
        acc = fmaf(xv.x, ev.x, acc);
        acc = fmaf(xv.y, ev.y, acc);
        acc = fmaf(xv.z, ev.z, acc);
        acc = fmaf(xv.w, ev.w, acc);
      }
      const float r = sxv + se[c];
      const float q = r - 2.0f * acc;
      if (q < bq || (q == bq && c < bc)) { bq = q; bc = c; }
    }
    bvv[tid] = bq;
    bii[tid] = bc;
    __syncthreads();
    for (int o = 128; o > 0; o >>= 1) {
      if (tid < o) {
        const float v2 = bvv[tid + o];
        const int c2 = bii[tid + o];
        if (v2 < bvv[tid] || (v2 == bvv[tid] && c2 < bii[tid])) {
          bvv[tid] = v2;
          bii[tid] = c2;
        }
      }
      __syncthreads();
    }
    if (tid == 0) {
      idx_i[t] = bii[0];
      idxf_out[t] = (float)bii[0];
    }
    __syncthreads();
  }
}

// ---------------- fallback argmin (tiny-ws path; round-4 kernel) ----------
__global__ __launch_bounds__(256) void argmin_fb_kernel(const float* __restrict__ x,
                                                        const float* __restrict__ cb,
                                                        const float* __restrict__ se,
                                                        const float* __restrict__ sx,
                                                        int* __restrict__ idx_out,
                                                        float* __restrict__ idxf_out) {
  __shared__ __attribute__((aligned(16))) float xs[64 * 128];
  __shared__ __attribute__((aligned(16))) float es[64 * 128];
  const int tid = threadIdx.x;
  const int lane = tid & 63;
  const int w = tid >> 6;
  const int wt = w & 1;
  const int wc = w >> 1;
  const int tgl = lane & 7;
  const int cgl = lane >> 3;
  const int t0 = wt * 64 + tgl * 8;
  const int c0 = wc * 64 + cgl * 8;
  const int tok0 = blockIdx.x * 128;
  float sxf[8];
#pragma unroll
  for (int i = 0; i < 8; ++i) sxf[i] = sx[tok0 + t0 + i];
  float bv[8];
  int bi[8];
#pragma unroll
  for (int i = 0; i < 8; ++i) { bv[i] = 3.4e38f; bi[i] = 0; }
  for (int ct = 0; ct < KCODES / 128; ++ct) {
    float acc[8][8] = {};
    for (int kt = 0; kt < 4; ++kt) {
      __syncthreads();
      {
        const float* xsrc = x + (size_t)tok0 * D + kt * 64;
        const float* esrc = cb + (size_t)(ct * 128) * D + kt * 64;
#pragma unroll
        for (int p = 0; p < 8; ++p) {
          const int idx = p * 256 + tid;
          const int t = idx >> 4;
          const int c = idx & 15;
          const int colp = (t + 8 * (c >> 1)) & 127;
          const float4 xv = *reinterpret_cast<const float4*>(xsrc + (size_t)t * D + c * 4);
          float* xd = &xs[(c * 4) * 128 + colp];
          xd[0] = xv.x; xd[128] = xv.y; xd[256] = xv.z; xd[384] = xv.w;
          const float4 ev = *reinterpret_cast<const float4*>(esrc + (size_t)t * D + c * 4);
          float* ed = &es[(c * 4) * 128 + colp];
          ed[0] = ev.x; ed[128] = ev.y; ed[256] = ev.z; ed[384] = ev.w;
        }
      }
      __syncthreads();
      for (int kp = 0; kp < 8; ++kp) {
        const float* xb = &xs[(kp * 8) * 128 + ((t0 + 8 * kp) & 127)];
        const float* eb = &es[(kp * 8) * 128 + ((c0 + 8 * kp) & 127)];
#pragma unroll
        for (int k2 = 0; k2 < 8; ++k2) {
          const float4 xv0 = *reinterpret_cast<const float4*>(xb + k2 * 128);
          const float4 xv1 = *reinterpret_cast<const float4*>(xb + k2 * 128 + 4);
          const float4 ev0 = *reinterpret_cast<const float4*>(eb + k2 * 128);
          const float4 ev1 = *reinterpret_cast<const float4*>(eb + k2 * 128 + 4);
          const float xa[8] = {xv0.x, xv0.y, xv0.z, xv0.w, xv1.x, xv1.y, xv1.z, xv1.w};
          const float ea[8] = {ev0.x, ev0.y, ev0.z, ev0.w, ev1.x, ev1.y, ev1.z, ev1.w};
#pragma unroll
          for (int i = 0; i < 8; ++i)
#pragma unroll
            for (int j = 0; j < 8; ++j) acc[i][j] = fmaf(xa[i], ea[j], acc[i][j]);
        }
      }
    }
#pragma unroll
    for (int j = 0; j < 8; ++j) {
      const int cidx = ct * 128 + c0 + j;
      const float sef = se[cidx];
#pragma unroll
      for (int i = 0; i < 8; ++i) {
        const float r = sxf[i] + sef;
        const float s = r - 2.0f * acc[i][j];
        if (s < bv[i]) { bv[i] = s; bi[i] = cidx; }
      }
    }
  }
  __syncthreads();
  float* red_val = xs;
  int* red_idx = reinterpret_cast<int*>(xs + 128 * 17);
  const int g = wc * 8 + cgl;
#pragma unroll
  for (int i = 0; i < 8; ++i) {
    red_val[(t0 + i) * 17 + g] = bv[i];
    red_idx[(t0 + i) * 17 + g] = bi[i];
  }
  __syncthreads();
  if (tid < 128) {
    float v = red_val[tid * 17 + 0];
    int ix = red_idx[tid * 17 + 0];
#pragma unroll
    for (int gg = 1; gg < 16; ++gg) {
      const float vv = red_val[tid * 17 + gg];
      const int ii = red_idx[tid * 17 + gg];
      if (vv < v || (vv == v && ii < ix)) { v = vv; ix = ii; }
    }
    idx_out[tok0 + tid] = ix;
    idxf_out[tok0 + tid] = (float)ix;
  }
}

// ---------------- kernel 4: gather, q_st, loss partials, histogram --------
__global__ __launch_bounds__(256) void finalize_kernel(const float* __restrict__ x,
                                                       const float* __restrict__ cb,
                                                       const int* __restrict__ idx,
                                                       float* __restrict__ q_out,
                                                       unsigned int* __restrict__ counts,
                                                       double* __restrict__ partials) {
  __shared__ double tok_s[16];
  const int tid = threadIdx.x;
  const int lt = tid >> 4;
  const int ld = tid & 15;
  const int t = blockIdx.x * 16 + lt;
  const int id = idx[t];
  const float* xp = x + (size_t)t * D + ld * 16;
  const float* ep = cb + (size_t)id * D + ld * 16;
  float* qp = q_out + (size_t)t * D + ld * 16;
  float s = 0.0f;
#pragma unroll
  for (int c = 0; c < 4; ++c) {
    const float4 xv = reinterpret_cast<const float4*>(xp)[c];
    const float4 ev = reinterpret_cast<const float4*>(ep)[c];
    const float d0 = ev.x - xv.x, d1 = ev.y - xv.y;
    const float d2 = ev.z - xv.z, d3 = ev.w - xv.w;
    s = fmaf(d0, d0, s);
    s = fmaf(d1, d1, s);
    s = fmaf(d2, d2, s);
    s = fmaf(d3, d3, s);
    float4 qv;  // q_st = x + (q - x), as the reference computes it
    qv.x = xv.x + d0;
    qv.y = xv.y + d1;
    qv.z = xv.z + d2;
    qv.w = xv.w + d3;
    reinterpret_cast<float4*>(qp)[c] = qv;
  }
#pragma unroll
  for (int o = 8; o > 0; o >>= 1) s += __shfl_down(s, o, 16);
  if (ld == 0) {
    atomicAdd(&counts[id], 1u);
    tok_s[lt] = (double)s;
  }
  __syncthreads();
  if (tid == 0) {
    double bs = 0.0;
    for (int i = 0; i < 16; ++i) bs += tok_s[i];
    partials[blockIdx.x] = bs;
  }
}

// ---------------- kernel 5: scalar reductions ----------------
__global__ __launch_bounds__(256) void final_kernel(const unsigned int* __restrict__ counts,
                                                    const double* __restrict__ partials,
                                                    float* __restrict__ loss_out,
                                                    float* __restrict__ perp_out) {
  __shared__ double sh[256];
  const int tid = threadIdx.x;
  double ls = 0.0;
  for (int i = tid; i < NTOK / 16; i += 256) ls += partials[i];
  sh[tid] = ls;
  __syncthreads();
#pragma unroll
  for (int o = 128; o > 0; o >>= 1) {
    if (tid < o) sh[tid] += sh[tid + o];
    __syncthreads();
  }
  if (tid == 0) *loss_out = (float)(sh[0] * (1.25 / (256.0 * 65536.0)));
  __syncthreads();
  double hs = 0.0;
  for (int i = tid; i < KCODES; i += 256) {
    const float p = (float)counts[i] / 65536.0f;
    hs += (double)(p * logf(p + 1e-10f));
  }
  sh[tid] = hs;
  __syncthreads();
#pragma unroll
  for (int o = 128; o > 0; o >>= 1) {
    if (tid < o) sh[tid] += sh[tid + o];
    __syncthreads();
  }
  if (tid == 0) *perp_out = expf((float)(-sh[0]));
}

extern "C" void kernel_launch(void* const* d_in, const int* in_sizes, int n_in,
                              void* d_out, int out_size, void* d_ws, size_t ws_size,
                              hipStream_t stream) {
  (void)in_sizes; (void)n_in; (void)out_size;
  const float* x = (const float*)d_in[0];
  const float* cb = (const float*)d_in[1];

  float* out = (float*)d_out;
  float* q_out = out;                                  // [0, 16777216)
  float* loss_out = out + (size_t)Q_ELEMS;             // [16777216]
  float* perp_out = out + (size_t)Q_ELEMS + 1;         // [16777217]
  float* idxf_out = out + (size_t)Q_ELEMS + 2;         // [16777218, +65536)

  // ws layout (bytes):
  //   se f32[4096]           @0
  //   counts u32[4096]       @16K
  //   partials f64[4096]     @32K
  //   idx i32[65536]         @128K
  //   sx f32[65536]          @384K  (fallback only)
  //   ovf_count u32          @640K
  //   ovf_list i32[65536]    @644K
  //   ccnt_g u32[65536]      @1M
  //   rm_g f32[65536]        @1.5M
  //   cand_g u32[65536*24]   @2M   (6MB)
  //   bpack bf16[4096*256]   @12M  (2MB)
  char* ws = (char*)d_ws;
  float* se = (float*)(ws + 0);
  unsigned int* counts = (unsigned int*)(ws + (16 << 10));
  double* partials = (double*)(ws + (32 << 10));
  int* idx_i = (int*)(ws + (128 << 10));
  float* sx = (float*)(ws + (384 << 10));
  unsigned int* ovf_count = (unsigned int*)(ws + (640 << 10));
  int* ovf_list = (int*)(ws + (644 << 10));
  unsigned int* ccnt_g = (unsigned int*)(ws + (1 << 20));
  float* rm_g = (float*)(ws + (3 << 19));
  unsigned int* cand_g = (unsigned int*)(ws + (2 << 20));
  unsigned short* bpack = (unsigned short*)(ws + (12 << 20));

  hipMemsetAsync(counts, 0, KCODES * sizeof(unsigned int), stream);
  hipMemsetAsync(ovf_count, 0, sizeof(unsigned int), stream);
  ee_kernel<<<KCODES / 4, 256, 0, stream>>>(cb, se);

  if (ws_size >= (size_t)20 * 1024 * 1024) {
    pack_e_kernel<<<64, 256, 0, stream>>>(cb, bpack);
    screen5_kernel<<<NTOK / 128, 256, 0, stream>>>(x, bpack, se, ccnt_g, cand_g,
                                                   rm_g);
    rescore_kernel<<<NTOK / 256, 256, 0, stream>>>(x, cb, se, ccnt_g, cand_g,
                                                   rm_g, idx_i, idxf_out,
                                                   ovf_count, ovf_list);
    ovf_kernel<<<64, 256, 0, stream>>>(x, cb, se, ovf_count, ovf_list,
                                       idx_i, idxf_out);
  } else {
    xx_kernel<<<NTOK / 4, 256, 0, stream>>>(x, sx);
    argmin_fb_kernel<<<NTOK / 128, 256, 0, stream>>>(x, cb, se, sx, idx_i, idxf_out);
  }
  finalize_kernel<<<NTOK / 16, 256, 0, stream>>>(x, cb, idx_i, q_out, counts, partials);
  final_kernel<<<1, 256, 0, stream>>>(counts, partials, loss_out, perp_out);
}

// Round 15
// 345.927 us; speedup vs baseline: 80.2881x; 1.0353x over previous
//
#include <hip/hip_runtime.h>
#include <hip/hip_bf16.h>
#include <cstdint>
#include <cstddef>

#define D 256
#define NTOK 65536
#define KCODES 4096
#define Q_ELEMS (NTOK * D)   // 16777216
#define DELTA 3.0e-4f
#define CAP 24

typedef short bf16x8 __attribute__((ext_vector_type(8)));
typedef float f32x4 __attribute__((ext_vector_type(4)));
typedef unsigned short ushort8 __attribute__((ext_vector_type(8)));

__device__ __forceinline__ void gload_lds16(const float* g, float* l) {
  __builtin_amdgcn_global_load_lds(
      (const __attribute__((address_space(1))) void*)(g),
      (__attribute__((address_space(3))) void*)(l), 16, 0, 0);
}
__device__ __forceinline__ unsigned short f2bf(float f) {
  __hip_bfloat16 h = __float2bfloat16(f);
  unsigned short u;
  __builtin_memcpy(&u, &h, 2);
  return u;
}
__device__ __forceinline__ float bf2f(unsigned short u) {
  __hip_bfloat16 h;
  __builtin_memcpy(&h, &u, 2);
  return __bfloat162float(h);
}

// ---------------- kernel 1a: codebook squared norms (f64 -> f32) ----------
__global__ __launch_bounds__(256) void ee_kernel(const float* __restrict__ cb,
                                                 float* __restrict__ se) {
  const int row = blockIdx.x * 4 + (threadIdx.x >> 6);
  const int lane = threadIdx.x & 63;
  const float4 v = reinterpret_cast<const float4*>(cb + (size_t)row * D)[lane];
  double s = (double)v.x * v.x + (double)v.y * v.y +
             (double)v.z * v.z + (double)v.w * v.w;
#pragma unroll
  for (int o = 32; o > 0; o >>= 1) s += __shfl_down(s, o, 64);
  if (lane == 0) se[row] = (float)s;
}

// ---------------- kernel 1b: token squared norms (fallback path only) -----
__global__ __launch_bounds__(256) void xx_kernel(const float* __restrict__ x,
                                                 float* __restrict__ sx) {
  const int row = blockIdx.x * 4 + (threadIdx.x >> 6);
  const int lane = threadIdx.x & 63;
  const float4 v = reinterpret_cast<const float4*>(x + (size_t)row * D)[lane];
  double s = (double)v.x * v.x + (double)v.y * v.y +
             (double)v.z * v.z + (double)v.w * v.w;
#pragma unroll
  for (int o = 32; o > 0; o >>= 1) s += __shfl_down(s, o, 64);
  if (lane == 0) sx[row] = (float)s;
}

// ---------------- kernel 1c: pack codebook e_hi -> LDS-image bf16 tiles ---
__global__ __launch_bounds__(256) void pack_e_kernel(const float* __restrict__ cb,
                                                     unsigned short* __restrict__ bpack) {
  const int gid = blockIdx.x * 256 + threadIdx.x;  // 16384 = 4096 codes x 4 kt
  const int c = gid >> 2;
  const int kt = gid & 3;
  const int row = c & 127;
  const int swz = (row & 7) << 3;
  unsigned short* dst = bpack + ((size_t)((c >> 7) * 4 + kt)) * 8192 + row * 64;
  const float* src = cb + (size_t)c * D + kt * 64;
#pragma unroll
  for (int j = 0; j < 8; ++j) {
    ushort8 o;
#pragma unroll
    for (int e = 0; e < 8; ++e) o[e] = f2bf(src[j * 8 + e]);
    *reinterpret_cast<ushort8*>(dst + ((j * 8) ^ swz)) = o;
  }
}

// ---------------- kernel 2: MFMA screening (r11's proven screen3) ---------
// 256 thr / 4 waves / 128 tokens per block; 512 blocks. Ring-3 bbuf (48KB),
// 2-deep prefetch, plain __syncthreads per unit; LDS 68.5KB -> 2 blocks/CU.
// Best-measured structure (227us, r11); six sync-structure variants r8-r14
// all landed 227-272 -> this is the structural floor at 8 waves/CU
// (grid-bound: 2048 waves = NTOK / 32 tokens-per-wave).
// d~ = se - 2*bf16(x).e_hi via mfma 16x16x32; candidates
// (bf16(score)<<16)|idx inserted when s <= running_min + DELTA.
// Capture bound: winner <= rm_final + 1.74e-4 + 6e-5 < DELTA = 3e-4.
__global__ __launch_bounds__(256, 2) void screen3_kernel(
    const float* __restrict__ x, const unsigned short* __restrict__ bpack,
    const float* __restrict__ se, unsigned int* __restrict__ ccnt_g,
    unsigned int* __restrict__ cand_g, float* __restrict__ rm_g) {
  __shared__ __attribute__((aligned(16))) unsigned short bbuf[3][8192];  // 48KB
  __shared__ __attribute__((aligned(16))) unsigned short se_lds[KCODES]; // 8KB
  __shared__ unsigned int cand[128][CAP];                                // 12KB
  __shared__ unsigned int ccnt[128];                                     // 0.5KB

  const int tid = threadIdx.x;
  const int lane = tid & 63;
  const int w = tid >> 6;    // 0..3
  const int l15 = lane & 15;
  const int kg = lane >> 4;  // 0..3
  const int tok0 = blockIdx.x * 128;

  if (tid < 128) ccnt[tid] = 0;
  {  // se -> bf16 LDS: each thread converts 16 values
    const float4* s4 = reinterpret_cast<const float4*>(se) + tid * 4;
    const float4 a = s4[0], b = s4[1], c = s4[2], d = s4[3];
    ushort8 o0, o1;
    o0[0] = f2bf(a.x); o0[1] = f2bf(a.y); o0[2] = f2bf(a.z); o0[3] = f2bf(a.w);
    o0[4] = f2bf(b.x); o0[5] = f2bf(b.y); o0[6] = f2bf(b.z); o0[7] = f2bf(b.w);
    o1[0] = f2bf(c.x); o1[1] = f2bf(c.y); o1[2] = f2bf(c.z); o1[3] = f2bf(c.w);
    o1[4] = f2bf(d.x); o1[5] = f2bf(d.y); o1[6] = f2bf(d.z); o1[7] = f2bf(d.w);
    *reinterpret_cast<ushort8*>(&se_lds[tid * 16]) = o0;
    *reinterpret_cast<ushort8*>(&se_lds[tid * 16 + 8]) = o1;
  }

  // A fragments (hi-only bf16): 2 row-groups x 8 ksteps, static indices
  bf16x8 ah[2][8];
#pragma unroll
  for (int gi = 0; gi < 2; ++gi) {
    const int t = tok0 + w * 32 + gi * 16 + l15;
    const float* xp = x + (size_t)t * D;
#pragma unroll
    for (int ks = 0; ks < 8; ++ks) {
      const float4 v0 = *reinterpret_cast<const float4*>(xp + ks * 32 + kg * 8);
      const float4 v1 = *reinterpret_cast<const float4*>(xp + ks * 32 + kg * 8 + 4);
      const float xv[8] = {v0.x, v0.y, v0.z, v0.w, v1.x, v1.y, v1.z, v1.w};
      bf16x8 h;
#pragma unroll
      for (int e = 0; e < 8; ++e) h[e] = (short)f2bf(xv[e]);
      ah[gi][ks] = h;
    }
  }

  // stage one 16KB unit: 4 waves x 4 chunks x (64 lanes x 16B)
  auto STAGE = [&](int u) {
    const char* s = (const char*)bpack + (size_t)u * 16384 + w * 4096 + lane * 16;
    char* d = (char*)&bbuf[u % 3][0] + w * 4096;
    gload_lds16((const float*)s, (float*)d);
    gload_lds16((const float*)(s + 1024), (float*)(d + 1024));
    gload_lds16((const float*)(s + 2048), (float*)(d + 2048));
    gload_lds16((const float*)(s + 3072), (float*)(d + 3072));
  };

  float rm[2][4];
#pragma unroll
  for (int fr = 0; fr < 2; ++fr)
#pragma unroll
    for (int q = 0; q < 4; ++q) rm[fr][q] = 3.4e38f;

  f32x4 acc[2][8];

  STAGE(0);
  STAGE(1);
  __syncthreads();  // units 0,1 resident; se/ccnt ready

  for (int ct4 = 0; ct4 < 32; ++ct4) {
#pragma unroll
    for (int kt = 0; kt < 4; ++kt) {  // kt compile-time: ah[] stays in VGPRs
      const int u = ct4 * 4 + kt;
      if (u + 2 < 128) STAGE(u + 2);
      if (kt == 0) {
#pragma unroll
        for (int fr = 0; fr < 2; ++fr)
#pragma unroll
          for (int fc = 0; fc < 8; ++fc) acc[fr][fc] = (f32x4){0.f, 0.f, 0.f, 0.f};
      }
      const unsigned short* bb = &bbuf[u % 3][0];
#pragma unroll
      for (int kh = 0; kh < 2; ++kh) {
        const int ks = kt * 2 + kh;  // compile-time
        bf16x8 bfrag[8];
#pragma unroll
        for (int fc = 0; fc < 8; ++fc) {
          const int row = fc * 16 + l15;
          const int off = row * 64 + ((kh * 32 + kg * 8) ^ ((row & 7) << 3));
          bfrag[fc] = *reinterpret_cast<const bf16x8*>(bb + off);
        }
#pragma unroll
        for (int fr = 0; fr < 2; ++fr)
#pragma unroll
          for (int fc = 0; fc < 8; ++fc)
            acc[fr][fc] = __builtin_amdgcn_mfma_f32_16x16x32_bf16(
                ah[fr][ks], bfrag[fc], acc[fr][fc], 0, 0, 0);
      }
      if (kt == 3) {  // code-tile ct4 finished: mins + candidate inserts
        float sef[8];
#pragma unroll
        for (int fc = 0; fc < 8; ++fc)
          sef[fc] = bf2f(se_lds[ct4 * 128 + fc * 16 + l15]);
#pragma unroll
        for (int fr = 0; fr < 2; ++fr)
#pragma unroll
          for (int q = 0; q < 4; ++q) {
            float m = fmaf(-2.0f, acc[fr][0][q], sef[0]);
#pragma unroll
            for (int fc = 1; fc < 8; ++fc)
              m = fminf(m, fmaf(-2.0f, acc[fr][fc][q], sef[fc]));
            m = fminf(m, __shfl_xor(m, 1, 64));
            m = fminf(m, __shfl_xor(m, 2, 64));
            m = fminf(m, __shfl_xor(m, 4, 64));
            m = fminf(m, __shfl_xor(m, 8, 64));
            rm[fr][q] = fminf(rm[fr][q], m);
            const float thr = rm[fr][q] + DELTA;
            const int tl = w * 32 + fr * 16 + kg * 4 + q;
#pragma unroll
            for (int fc = 0; fc < 8; ++fc) {
              const float s = fmaf(-2.0f, acc[fr][fc][q], sef[fc]);
              if (s <= thr) {
                const unsigned p = atomicAdd(&ccnt[tl], 1u);
                if (p < CAP)
                  cand[tl][p] = ((unsigned)f2bf(s) << 16) |
                                (unsigned)(ct4 * 128 + fc * 16 + l15);
              }
            }
          }
      }
      __syncthreads();  // next unit resident; ring slot (u%3) free for reuse
    }
  }

  if (tid < 128) ccnt_g[tok0 + tid] = ccnt[tid];
  if (l15 == 0) {
#pragma unroll
    for (int fr = 0; fr < 2; ++fr)
#pragma unroll
      for (int q = 0; q < 4; ++q)
        rm_g[tok0 + w * 32 + fr * 16 + kg * 4 + q] = rm[fr][q];
  }
  for (int j = tid; j < 128 * CAP; j += 256)
    cand_g[(size_t)tok0 * CAP + j] = cand[j / CAP][j % CAP];
}

// ---------------- kernel 3: rescore with single-survivor fast path --------
// One thread per token. Capture bound: the reference argmin is ALWAYS among
// the filter survivors (bf16 screen score <= rm+DELTA). If exactly ONE
// candidate survives the filter, it IS the argmin -> no sx, no exact chain,
// no x/cb read (~85-90% of tokens: typical top-2 gap 1.1e-3 >> 3e-4 window).
// Multi-survivor tokens run the bit-exact reference chain: inline f64 sx
// (bit-safe: se < half-ulp(sx) => fl(sx+se)=sx, argmin sx-invariant; r9/r13
// passing runs), sequential fmaf chain d=0..255,
// dist = fl(fl(sx+se)-2*dot), lex-min (dist, idx).
__global__ __launch_bounds__(256) void rescore_kernel(
    const float* __restrict__ x, const float* __restrict__ cb,
    const float* __restrict__ se, const unsigned int* __restrict__ ccnt_g,
    const unsigned int* __restrict__ cand_g, const float* __restrict__ rm_g,
    int* __restrict__ idx_i, float* __restrict__ idxf_out,
    unsigned int* __restrict__ ovf_count, int* __restrict__ ovf_list) {
  const int t = blockIdx.x * 256 + threadIdx.x;
  const unsigned n = ccnt_g[t];
  if (n > CAP) {  // list overflowed: defer to full-scan fallback
    const unsigned p = atomicAdd(ovf_count, 1u);
    ovf_list[p] = t;
    return;
  }
  const float thr = rm_g[t] + DELTA;
  // pass 1: count filter survivors
  int surv = 0;
  int only_c = 0x7fffffff;
  for (unsigned k = 0; k < n; ++k) {
    const unsigned pk = cand_g[(size_t)t * CAP + k];
    if (bf2f((unsigned short)(pk >> 16)) <= thr) {
      ++surv;
      only_c = (int)(pk & 0xFFFFu);
    }
  }
  int bc;
  if (surv == 1) {
    bc = only_c;  // unique survivor == reference argmin; no chains needed
  } else {
    const float4* xp = reinterpret_cast<const float4*>(x + (size_t)t * D);
    double sxd = 0.0;
    for (int d4 = 0; d4 < 64; ++d4) {
      const float4 v = xp[d4];
      sxd += (double)v.x * v.x + (double)v.y * v.y +
             (double)v.z * v.z + (double)v.w * v.w;
    }
    const float sxv = (float)sxd;
    float bq = 3.4e38f;
    bc = 0x7fffffff;
    for (unsigned k = 0; k < n; ++k) {
      const unsigned pk = cand_g[(size_t)t * CAP + k];
      if (bf2f((unsigned short)(pk >> 16)) > thr) continue;
      const int c = (int)(pk & 0xFFFFu);
      const float4* cp = reinterpret_cast<const float4*>(cb + (size_t)c * D);
      float acc = 0.0f;
#pragma unroll 8
      for (int d4 = 0; d4 < 64; ++d4) {
        const float4 xv = xp[d4];
        const float4 ev = cp[d4];
        acc = fmaf(xv.x, ev.x, acc);
        acc = fmaf(xv.y, ev.y, acc);
        acc = fmaf(xv.z, ev.z, acc);
        acc = fmaf(xv.w, ev.w, acc);
      }
      const float r = sxv + se[c];
      const float q = r - 2.0f * acc;
      if (q < bq || (q == bq && c < bc)) { bq = q; bc = c; }
    }
  }
  idx_i[t] = bc;
  idxf_out[t] = (float)bc;
}

// ---------------- kernel 3b: full-scan fallback for overflowed tokens -----
__global__ __launch_bounds__(256) void ovf_kernel(
    const float* __restrict__ x, const float* __restrict__ cb,
    const float* __restrict__ se, const unsigned int* __restrict__ ovf_count,
    const int* __restrict__ ovf_list, int* __restrict__ idx_i,
    float* __restrict__ idxf_out) {
  __shared__ float bvv[256];
  __shared__ int bii[256];
  __shared__ double shd[256];
  const int tid = threadIdx.x;
  const unsigned cnt = *ovf_count;
  for (unsigned i = blockIdx.x; i < cnt; i += gridDim.x) {
    const int t = ovf_list[i];
    const float xv1 = x[(size_t)t * D + tid];
    shd[tid] = (double)xv1 * xv1;
    __syncthreads();
    for (int o = 128; o > 0; o >>= 1) {
      if (tid < o) shd[tid] += shd[tid + o];
      __syncthreads();
    }
    const float sxv = (float)shd[0];
    __syncthreads();
    const float4* xp = reinterpret_cast<const float4*>(x + (size_t)t * D);
    float bq = 3.4e38f;
    int bc = 0x7fffffff;
    for (int c = tid; c < KCODES; c += 256) {
      const float4* cp = reinterpret_cast<const float4*>(cb + (size_t)c * D);
      float acc = 0.0f;
#pragma unroll 8
      for (int d4 = 0; d4 < 64; ++d4) {
        const float4 xv = xp[d4];
        const float4 ev = cp[d4];
        acc = fmaf(xv.x, ev.x, acc);
        acc = fmaf(xv.y, ev.y, acc);
        acc = fmaf(xv.z, ev.z, acc);
        acc = fmaf(xv.w, ev.w, acc);
      }
      const float r = sxv + se[c];
      const float q = r - 2.0f * acc;
      if (q < bq || (q == bq && c < bc)) { bq = q; bc = c; }
    }
    bvv[tid] = bq;
    bii[tid] = bc;
    __syncthreads();
    for (int o = 128; o > 0; o >>= 1) {
      if (tid < o) {
        const float v2 = bvv[tid + o];
        const int c2 = bii[tid + o];
        if (v2 < bvv[tid] || (v2 == bvv[tid] && c2 < bii[tid])) {
          bvv[tid] = v2;
          bii[tid] = c2;
        }
      }
      __syncthreads();
    }
    if (tid == 0) {
      idx_i[t] = bii[0];
      idxf_out[t] = (float)bii[0];
    }
    __syncthreads();
  }
}

// ---------------- fallback argmin (tiny-ws path; round-4 kernel) ----------
__global__ __launch_bounds__(256) void argmin_fb_kernel(const float* __restrict__ x,
                                                        const float* __restrict__ cb,
                                                        const float* __restrict__ se,
                                                        const float* __restrict__ sx,
                                                        int* __restrict__ idx_out,
                                                        float* __restrict__ idxf_out) {
  __shared__ __attribute__((aligned(16))) float xs[64 * 128];
  __shared__ __attribute__((aligned(16))) float es[64 * 128];
  const int tid = threadIdx.x;
  const int lane = tid & 63;
  const int w = tid >> 6;
  const int wt = w & 1;
  const int wc = w >> 1;
  const int tgl = lane & 7;
  const int cgl = lane >> 3;
  const int t0 = wt * 64 + tgl * 8;
  const int c0 = wc * 64 + cgl * 8;
  const int tok0 = blockIdx.x * 128;
  float sxf[8];
#pragma unroll
  for (int i = 0; i < 8; ++i) sxf[i] = sx[tok0 + t0 + i];
  float bv[8];
  int bi[8];
#pragma unroll
  for (int i = 0; i < 8; ++i) { bv[i] = 3.4e38f; bi[i] = 0; }
  for (int ct = 0; ct < KCODES / 128; ++ct) {
    float acc[8][8] = {};
    for (int kt = 0; kt < 4; ++kt) {
      __syncthreads();
      {
        const float* xsrc = x + (size_t)tok0 * D + kt * 64;
        const float* esrc = cb + (size_t)(ct * 128) * D + kt * 64;
#pragma unroll
        for (int p = 0; p < 8; ++p) {
          const int idx = p * 256 + tid;
          const int t = idx >> 4;
          const int c = idx & 15;
          const int colp = (t + 8 * (c >> 1)) & 127;
          const float4 xv = *reinterpret_cast<const float4*>(xsrc + (size_t)t * D + c * 4);
          float* xd = &xs[(c * 4) * 128 + colp];
          xd[0] = xv.x; xd[128] = xv.y; xd[256] = xv.z; xd[384] = xv.w;
          const float4 ev = *reinterpret_cast<const float4*>(esrc + (size_t)t * D + c * 4);
          float* ed = &es[(c * 4) * 128 + colp];
          ed[0] = ev.x; ed[128] = ev.y; ed[256] = ev.z; ed[384] = ev.w;
        }
      }
      __syncthreads();
      for (int kp = 0; kp < 8; ++kp) {
        const float* xb = &xs[(kp * 8) * 128 + ((t0 + 8 * kp) & 127)];
        const float* eb = &es[(kp * 8) * 128 + ((c0 + 8 * kp) & 127)];
#pragma unroll
        for (int k2 = 0; k2 < 8; ++k2) {
          const float4 xv0 = *reinterpret_cast<const float4*>(xb + k2 * 128);
          const float4 xv1 = *reinterpret_cast<const float4*>(xb + k2 * 128 + 4);
          const float4 ev0 = *reinterpret_cast<const float4*>(eb + k2 * 128);
          const float4 ev1 = *reinterpret_cast<const float4*>(eb + k2 * 128 + 4);
          const float xa[8] = {xv0.x, xv0.y, xv0.z, xv0.w, xv1.x, xv1.y, xv1.z, xv1.w};
          const float ea[8] = {ev0.x, ev0.y, ev0.z, ev0.w, ev1.x, ev1.y, ev1.z, ev1.w};
#pragma unroll
          for (int i = 0; i < 8; ++i)
#pragma unroll
            for (int j = 0; j < 8; ++j) acc[i][j] = fmaf(xa[i], ea[j], acc[i][j]);
        }
      }
    }
#pragma unroll
    for (int j = 0; j < 8; ++j) {
      const int cidx = ct * 128 + c0 + j;
      const float sef = se[cidx];
#pragma unroll
      for (int i = 0; i < 8; ++i) {
        const float r = sxf[i] + sef;
        const float s = r - 2.0f * acc[i][j];
        if (s < bv[i]) { bv[i] = s; bi[i] = cidx; }
      }
    }
  }
  __syncthreads();
  float* red_val = xs;
  int* red_idx = reinterpret_cast<int*>(xs + 128 * 17);
  const int g = wc * 8 + cgl;
#pragma unroll
  for (int i = 0; i < 8; ++i) {
    red_val[(t0 + i) * 17 + g] = bv[i];
    red_idx[(t0 + i) * 17 + g] = bi[i];
  }
  __syncthreads();
  if (tid < 128) {
    float v = red_val[tid * 17 + 0];
    int ix = red_idx[tid * 17 + 0];
#pragma unroll
    for (int gg = 1; gg < 16; ++gg) {
      const float vv = red_val[tid * 17 + gg];
      const int ii = red_idx[tid * 17 + gg];
      if (vv < v || (vv == v && ii < ix)) { v = vv; ix = ii; }
    }
    idx_out[tok0 + tid] = ix;
    idxf_out[tok0 + tid] = (float)ix;
  }
}

// ---------------- kernel 4: gather, q_st, loss partials, histogram --------
__global__ __launch_bounds__(256) void finalize_kernel(const float* __restrict__ x,
                                                       const float* __restrict__ cb,
                                                       const int* __restrict__ idx,
                                                       float* __restrict__ q_out,
                                                       unsigned int* __restrict__ counts,
                                                       double* __restrict__ partials) {
  __shared__ double tok_s[16];
  const int tid = threadIdx.x;
  const int lt = tid >> 4;
  const int ld = tid & 15;
  const int t = blockIdx.x * 16 + lt;
  const int id = idx[t];
  const float* xp = x + (size_t)t * D + ld * 16;
  const float* ep = cb + (size_t)id * D + ld * 16;
  float* qp = q_out + (size_t)t * D + ld * 16;
  float s = 0.0f;
#pragma unroll
  for (int c = 0; c < 4; ++c) {
    const float4 xv = reinterpret_cast<const float4*>(xp)[c];
    const float4 ev = reinterpret_cast<const float4*>(ep)[c];
    const float d0 = ev.x - xv.x, d1 = ev.y - xv.y;
    const float d2 = ev.z - xv.z, d3 = ev.w - xv.w;
    s = fmaf(d0, d0, s);
    s = fmaf(d1, d1, s);
    s = fmaf(d2, d2, s);
    s = fmaf(d3, d3, s);
    float4 qv;  // q_st = x + (q - x), as the reference computes it
    qv.x = xv.x + d0;
    qv.y = xv.y + d1;
    qv.z = xv.z + d2;
    qv.w = xv.w + d3;
    reinterpret_cast<float4*>(qp)[c] = qv;
  }
#pragma unroll
  for (int o = 8; o > 0; o >>= 1) s += __shfl_down(s, o, 16);
  if (ld == 0) {
    atomicAdd(&counts[id], 1u);
    tok_s[lt] = (double)s;
  }
  __syncthreads();
  if (tid == 0) {
    double bs = 0.0;
    for (int i = 0; i < 16; ++i) bs += tok_s[i];
    partials[blockIdx.x] = bs;
  }
}

// ---------------- kernel 5: scalar reductions ----------------
__global__ __launch_bounds__(256) void final_kernel(const unsigned int* __restrict__ counts,
                                                    const double* __restrict__ partials,
                                                    float* __restrict__ loss_out,
                                                    float* __restrict__ perp_out) {
  __shared__ double sh[256];
  const int tid = threadIdx.x;
  double ls = 0.0;
  for (int i = tid; i < NTOK / 16; i += 256) ls += partials[i];
  sh[tid] = ls;
  __syncthreads();
#pragma unroll
  for (int o = 128; o > 0; o >>= 1) {
    if (tid < o) sh[tid] += sh[tid + o];
    __syncthreads();
  }
  if (tid == 0) *loss_out = (float)(sh[0] * (1.25 / (256.0 * 65536.0)));
  __syncthreads();
  double hs = 0.0;
  for (int i = tid; i < KCODES; i += 256) {
    const float p = (float)counts[i] / 65536.0f;
    hs += (double)(p * logf(p + 1e-10f));
  }
  sh[tid] = hs;
  __syncthreads();
#pragma unroll
  for (int o = 128; o > 0; o >>= 1) {
    if (tid < o) sh[tid] += sh[tid + o];
    __syncthreads();
  }
  if (tid == 0) *perp_out = expf((float)(-sh[0]));
}

extern "C" void kernel_launch(void* const* d_in, const int* in_sizes, int n_in,
                              void* d_out, int out_size, void* d_ws, size_t ws_size,
                              hipStream_t stream) {
  (void)in_sizes; (void)n_in; (void)out_size;
  const float* x = (const float*)d_in[0];
  const float* cb = (const float*)d_in[1];

  float* out = (float*)d_out;
  float* q_out = out;                                  // [0, 16777216)
  float* loss_out = out + (size_t)Q_ELEMS;             // [16777216]
  float* perp_out = out + (size_t)Q_ELEMS + 1;         // [16777217]
  float* idxf_out = out + (size_t)Q_ELEMS + 2;         // [16777218, +65536)

  // ws layout (bytes):
  //   se f32[4096]           @0
  //   counts u32[4096]       @16K
  //   partials f64[4096]     @32K
  //   idx i32[65536]         @128K
  //   sx f32[65536]          @384K  (fallback only)
  //   ovf_count u32          @640K
  //   ovf_list i32[65536]    @644K
  //   ccnt_g u32[65536]      @1M
  //   rm_g f32[65536]        @1.5M
  //   cand_g u32[65536*24]   @2M   (6MB)
  //   bpack bf16[4096*256]   @12M  (2MB)
  char* ws = (char*)d_ws;
  float* se = (float*)(ws + 0);
  unsigned int* counts = (unsigned int*)(ws + (16 << 10));
  double* partials = (double*)(ws + (32 << 10));
  int* idx_i = (int*)(ws + (128 << 10));
  float* sx = (float*)(ws + (384 << 10));
  unsigned int* ovf_count = (unsigned int*)(ws + (640 << 10));
  int* ovf_list = (int*)(ws + (644 << 10));
  unsigned int* ccnt_g = (unsigned int*)(ws + (1 << 20));
  float* rm_g = (float*)(ws + (3 << 19));
  unsigned int* cand_g = (unsigned int*)(ws + (2 << 20));
  unsigned short* bpack = (unsigned short*)(ws + (12 << 20));

  hipMemsetAsync(counts, 0, KCODES * sizeof(unsigned int), stream);
  hipMemsetAsync(ovf_count, 0, sizeof(unsigned int), stream);
  ee_kernel<<<KCODES / 4, 256, 0, stream>>>(cb, se);

  if (ws_size >= (size_t)20 * 1024 * 1024) {
    pack_e_kernel<<<64, 256, 0, stream>>>(cb, bpack);
    screen3_kernel<<<NTOK / 128, 256, 0, stream>>>(x, bpack, se, ccnt_g, cand_g,
                                                   rm_g);
    rescore_kernel<<<NTOK / 256, 256, 0, stream>>>(x, cb, se, ccnt_g, cand_g,
                                                   rm_g, idx_i, idxf_out,
                                                   ovf_count, ovf_list);
    ovf_kernel<<<64, 256, 0, stream>>>(x, cb, se, ovf_count, ovf_list,
                                       idx_i, idxf_out);
  } else {
    xx_kernel<<<NTOK / 4, 256, 0, stream>>>(x, sx);
    argmin_fb_kernel<<<NTOK / 128, 256, 0, stream>>>(x, cb, se, sx, idx_i, idxf_out);
  }
  finalize_kernel<<<NTOK / 16, 256, 0, stream>>>(x, cb, idx_i, q_out, counts, partials);
  final_kernel<<<1, 256, 0, stream>>>(counts, partials, loss_out, perp_out);
}